// Round 15
// baseline (364.912 us; speedup 1.0000x reference)
//
#include <hip/hip_runtime.h>

// GAT 3-layer forward, MI355X gfx950.
// R15: attention logits FUSED into GEMM epilogues (atomicAdd of per-wave
// shfl-reduced partials into zeroed als/ald) -- removes logits2/logits3
// dispatches and their 45MB of re-reads. Rest frozen from R14.

typedef __attribute__((ext_vector_type(8))) short bf16x8;
typedef __attribute__((ext_vector_type(4))) float f32x4;

#define DEVINL __device__ __forceinline__

static constexpr int NN   = 10000;
static constexpr int NE   = 160000;
static constexpr int MPAD = 10240;   // 16*640, 80*128
static constexpr int DIN  = 64;
static constexpr int CCH  = 256;
static constexpr int NH   = 8;
static constexpr int F12  = 2048;    // NH * CCH

DEVINL unsigned short f2bf(float x){
  unsigned u = __float_as_uint(x);
  u += 0x7fffu + ((u >> 16) & 1u);           // RNE
  return (unsigned short)(u >> 16);
}
DEVINL float bf2f(unsigned short h){ return __uint_as_float(((unsigned)h) << 16); }

DEVINL void gload_lds16(const unsigned short* g, unsigned short* lds){
  __builtin_amdgcn_global_load_lds(
      (__attribute__((address_space(1))) unsigned int*)(g),
      (__attribute__((address_space(3))) unsigned int*)(lds), 16, 0, 0);
}

// ---- W [K][Nn] f32 -> Wt [Nn][K] bf16
__global__ __launch_bounds__(256) void transpose_cvt_kernel(const float* __restrict__ W,
                                                            unsigned short* __restrict__ Wt,
                                                            int K, int Nn){
  __shared__ float tile[32][33];
  int k0 = blockIdx.x*32, n0 = blockIdx.y*32;
  int tx = threadIdx.x & 31, ty = threadIdx.x >> 5;
  #pragma unroll
  for (int r = ty; r < 32; r += 8) tile[r][tx] = W[(size_t)(k0+r)*Nn + n0 + tx];
  __syncthreads();
  #pragma unroll
  for (int r = ty; r < 32; r += 8) Wt[(size_t)(n0+r)*K + k0 + tx] = f2bf(tile[tx][r]);
}

// ---- CSR build
__global__ __launch_bounds__(256) void hist_kernel(const int* __restrict__ dst,
                                                   int* __restrict__ deg, int E_){
  int i = blockIdx.x*256 + threadIdx.x;
  if (i < E_) atomicAdd(&deg[dst[i]], 1);
}

__global__ __launch_bounds__(256) void scan_kernel(const int* __restrict__ deg,
                                                   int* __restrict__ off, int n){
  const int CH = (n + 255) / 256;
  int t = threadIdx.x;
  int lo = t*CH, hi = min(lo + CH, n);
  int s = 0;
  for (int i = lo; i < hi; i++) s += deg[i];
  __shared__ int ws[256];
  ws[t] = s;
  __syncthreads();
  for (int d = 1; d < 256; d <<= 1){
    int v = (t >= d) ? ws[t-d] : 0;
    __syncthreads();
    ws[t] += v;
    __syncthreads();
  }
  int run = ws[t] - s;
  for (int i = lo; i < hi; i++){ off[i] = run; run += deg[i]; }
  if (t == 255) off[n] = ws[255];
}

__global__ __launch_bounds__(256) void scatter_kernel(const int* __restrict__ src,
                                                      const int* __restrict__ dst,
                                                      const int* __restrict__ off,
                                                      int* __restrict__ cursor,
                                                      int* __restrict__ csrc, int E_){
  int i = blockIdx.x*256 + threadIdx.x;
  if (i >= E_) return;
  int d = dst[i];
  int pI = atomicAdd(&cursor[d], 1);
  csrc[off[d] + pI] = src[i];
}

// ---- Wa1[c][i] = sum_j W1[c][h*256+j] * a1{s,d}[h][j]
__global__ __launch_bounds__(256) void wa1_kernel(const float* __restrict__ W1,
                                                  const float* __restrict__ a1s,
                                                  const float* __restrict__ a1d,
                                                  float* __restrict__ Wa1){
  int t = blockIdx.x*256 + threadIdx.x;
  if (t >= 64*16) return;
  int c = t >> 4, i = t & 15;
  int h = i & 7;
  const float* a = (i < 8) ? a1s : a1d;
  float s = 0.f;
  #pragma unroll 8
  for (int j = 0; j < 256; j++) s = fmaf(W1[(size_t)c*F12 + h*256 + j], a[h*256 + j], s);
  Wa1[c*16 + i] = s;
}

// ---- layer-1 logits straight from x
__global__ __launch_bounds__(256) void logits1_kernel(const float* __restrict__ x,
                                                      const float* __restrict__ Wa1,
                                                      float* __restrict__ als,
                                                      float* __restrict__ ald){
  __shared__ float wa[64*16];
  for (int i = threadIdx.x; i < 64*16; i += 256) wa[i] = Wa1[i];
  __syncthreads();
  int gid = blockIdx.x*256 + threadIdx.x;
  int v = gid >> 4, i = gid & 15;
  if (v >= NN) return;
  float s = 0.f;
  #pragma unroll
  for (int c = 0; c < 64; c++) s = fmaf(x[(size_t)v*64 + c], wa[c*16 + i], s);
  if (i < 8) als[v*8 + i] = s;
  else       ald[v*8 + (i - 8)] = s;
}

// ---- layer-1 aggregation (R13): lane=(edge_slot,head) softmax, LDS alpha stage
__global__ __launch_bounds__(256) void agg1_kernel(const float* __restrict__ x,
                                                   const int* __restrict__ off,
                                                   const int* __restrict__ csrc,
                                                   const float* __restrict__ als,
                                                   const float* __restrict__ ald,
                                                   unsigned short* __restrict__ Xa){
  const int wv = threadIdx.x >> 6, lane = threadIdx.x & 63;
  const int v = blockIdx.x*4 + wv;
  if (v >= NN) return;
  const int e0 = off[v], deg = off[v+1] - e0;
  const int h  = lane & 7;
  const int es = lane >> 3;

  __shared__ float al_sh[4][64];
  __shared__ int   u_sh[4][8];

  const float aldv = ald[v*8 + h];

  float m = -1e30f, s = 0.f;
  for (int i = es; i < deg; i += 8){
    int u = csrc[e0 + i];
    float xe = als[u*8 + h] + aldv;
    xe = xe > 0.f ? xe : 0.2f*xe;
    float nm = fmaxf(m, xe);
    s = s*__expf(m - nm) + __expf(xe - nm);
    m = nm;
  }
  #pragma unroll
  for (int d = 8; d < 64; d <<= 1){
    float mo = __shfl_xor(m, d);
    float so = __shfl_xor(s, d);
    float nm = fmaxf(m, mo);
    s = s*__expf(m - nm) + so*__expf(mo - nm);
    m = nm;
  }
  const float sinv = 1.f / (s + 1e-16f);

  float acc[8];
  #pragma unroll
  for (int hh = 0; hh < 8; hh++) acc[hh] = 0.f;

  const int nfull = deg & ~7;
  for (int base = 0; base < nfull; base += 8){
    int u = csrc[e0 + base + es];
    if (h == 0) u_sh[wv][es] = u;
    float xe = als[u*8 + h] + aldv;
    xe = xe > 0.f ? xe : 0.2f*xe;
    al_sh[wv][es*8 + h] = __expf(xe - m) * sinv;
    #pragma unroll
    for (int j = 0; j < 8; j++){
      float xv = x[(size_t)u_sh[wv][j]*64 + lane];
      #pragma unroll
      for (int hh = 0; hh < 8; hh++)
        acc[hh] = fmaf(al_sh[wv][j*8 + hh], xv, acc[hh]);
    }
  }
  if (nfull < deg){
    const int nch = deg - nfull;
    if (es < nch){
      int u = csrc[e0 + nfull + es];
      if (h == 0) u_sh[wv][es] = u;
      float xe = als[u*8 + h] + aldv;
      xe = xe > 0.f ? xe : 0.2f*xe;
      al_sh[wv][es*8 + h] = __expf(xe - m) * sinv;
    }
    for (int j = 0; j < nch; j++){
      float xv = x[(size_t)u_sh[wv][j]*64 + lane];
      #pragma unroll
      for (int hh = 0; hh < 8; hh++)
        acc[hh] = fmaf(al_sh[wv][j*8 + hh], xv, acc[hh]);
    }
  }

  #pragma unroll
  for (int hh = 0; hh < 8; hh++)
    Xa[(size_t)v*512 + hh*64 + lane] = f2bf(acc[hh]);
}

// ---- layer-1 GEMM per head with fused bias+ELU
__global__ __launch_bounds__(256) void gemm_l1_kernel(
    const unsigned short* __restrict__ Xa,    // [MPAD][8][64]
    const unsigned short* __restrict__ Wt1,   // [2048][64]
    const float* __restrict__ b1,
    unsigned short* __restrict__ actA)        // [MPAD][2048]
{
  __shared__ __align__(16) unsigned short As[2][128*32];
  __shared__ __align__(16) unsigned short Bs[2][256*32];
  const int wave = threadIdx.x >> 6, lane = threadIdx.x & 63;
  const int wm = wave >> 1, wn = wave & 1;
  const size_t m0 = (size_t)blockIdx.x * 128;
  const int h = blockIdx.y;
  const int lr = lane >> 2, l3 = lane & 3;

  #pragma unroll
  for (int sB = 0; sB < 2; sB++){
    #pragma unroll
    for (int j = 0; j < 2; j++){
      int rb = (wave*2 + j)*16;
      int row = rb + lr;
      int kc = l3 ^ ((row >> 1) & 3);
      gload_lds16(Xa + (m0 + row)*512 + h*64 + sB*32 + kc*8, &As[sB][rb*32]);
    }
    #pragma unroll
    for (int j = 0; j < 4; j++){
      int rb = (wave*4 + j)*16;
      int row = rb + lr;
      int kc = l3 ^ ((row >> 1) & 3);
      gload_lds16(Wt1 + (size_t)(h*256 + row)*64 + sB*32 + kc*8, &Bs[sB][rb*32]);
    }
  }
  asm volatile("s_waitcnt vmcnt(0)" ::: "memory");
  __syncthreads();

  f32x4 acc[4][8];
  #pragma unroll
  for (int i = 0; i < 4; i++)
    #pragma unroll
    for (int j = 0; j < 8; j++) acc[i][j] = (f32x4){0.f,0.f,0.f,0.f};

  const int rl = lane & 15, q = lane >> 4;
  #pragma unroll
  for (int sB = 0; sB < 2; sB++){
    bf16x8 af[4], bfr[8];
    #pragma unroll
    for (int mm = 0; mm < 4; mm++){
      int row = wm*64 + mm*16 + rl;
      int ch = q ^ ((row >> 1) & 3);
      af[mm] = *(const bf16x8*)&As[sB][row*32 + ch*8];
    }
    #pragma unroll
    for (int n = 0; n < 8; n++){
      int row = wn*128 + n*16 + rl;
      int ch = q ^ ((row >> 1) & 3);
      bfr[n] = *(const bf16x8*)&Bs[sB][row*32 + ch*8];
    }
    #pragma unroll
    for (int mm = 0; mm < 4; mm++)
      #pragma unroll
      for (int n = 0; n < 8; n++)
        acc[mm][n] = __builtin_amdgcn_mfma_f32_16x16x32_bf16(af[mm], bfr[n], acc[mm][n], 0, 0, 0);
  }

  #pragma unroll
  for (int mm = 0; mm < 4; mm++)
    #pragma unroll
    for (int n = 0; n < 8; n++)
      #pragma unroll
      for (int r = 0; r < 4; r++){
        size_t row = m0 + wm*64 + mm*16 + q*4 + r;
        int col = wn*128 + n*16 + rl;
        float o = acc[mm][n][r] + b1[h*256 + col];
        o = o > 0.f ? o : (__expf(o) - 1.f);
        actA[row*F12 + h*256 + col] = f2bf(o);
      }
}

// ---- layer-2 GEMM (R11 config) + FUSED logits2.
// BM=640, BN=128, BK=32 -> grid 256 = 1/CU. Head-major C. Epilogue also
// accumulates als/ald partials (per-wave 64-col dot with as2/ad2, rl-group
// shfl reduce, atomicAdd). als/ald must be zeroed before launch.
__global__ __launch_bounds__(512, 1) void gemm_l2_kernel(
    const unsigned short* __restrict__ A,
    const unsigned short* __restrict__ Bt,
    unsigned short* __restrict__ Chm,         // [8][MPAD][256]
    const float* __restrict__ as2,            // [8][256]
    const float* __restrict__ ad2,            // [8][256]
    float* __restrict__ als,                  // [NN][8] (zeroed)
    float* __restrict__ ald,                  // [NN][8] (zeroed)
    int K)
{
  __shared__ __align__(16) unsigned short As[3][640*32];   // 3 x 40KB
  __shared__ __align__(16) unsigned short Bs[3][128*32];   // 3 x 8KB

  const int tid  = threadIdx.x;
  const int wave = tid >> 6, lane = tid & 63;
  const int wm = wave >> 1, wn = wave & 1;          // 4Mx2N, per-wave 160x64

  const int orig = blockIdx.x;
  const int wg   = (orig & 7) * 32 + (orig >> 3);
  const size_t m0 = (size_t)(wg >> 4) * 640;
  const size_t n0 = (size_t)(wg & 15) * 128;

  f32x4 acc[10][4];
  #pragma unroll
  for (int i = 0; i < 10; i++)
    #pragma unroll
    for (int j = 0; j < 4; j++) acc[i][j] = (f32x4){0.f,0.f,0.f,0.f};

  const int lr = lane >> 2;
  const int l3 = lane & 3;

  auto stageA = [&](int slot, int k0, int j){
    const int rb  = (wave*5 + j) * 16;
    const int row = rb + lr;
    const int kc  = l3 ^ ((row >> 1) & 3);
    gload_lds16(A + (m0 + row)*(size_t)K + k0 + kc*8, &As[slot][rb*32]);
  };
  auto stageB = [&](int slot, int k0){
    const int rb  = wave * 16;
    const int row = rb + lr;
    const int kc  = l3 ^ ((row >> 1) & 3);
    gload_lds16(Bt + (n0 + row)*(size_t)K + k0 + kc*8, &Bs[slot][rb*32]);
  };
  auto stageTile = [&](int T){
    const int slot = T % 3, k0 = T << 5;
    #pragma unroll
    for (int j = 0; j < 5; j++) stageA(slot, k0, j);
    stageB(slot, k0);
  };

  const int nt = K >> 5;            // 64
  stageTile(0);
  stageTile(1);

  const int rl = lane & 15;
  const int q  = lane >> 4;

  for (int T = 0; T < nt; ++T){
    if (T + 1 < nt) asm volatile("s_waitcnt vmcnt(6)" ::: "memory");
    else            asm volatile("s_waitcnt vmcnt(0)" ::: "memory");
    __builtin_amdgcn_s_barrier();

    const int slot = T % 3;
    const bool st  = (T + 2 < nt);
    const int s2   = (T + 2) % 3;
    const int k2   = (T + 2) << 5;

    bf16x8 bfr[4], af[5];
    #pragma unroll
    for (int n = 0; n < 4; n++){
      const int row = wn*64 + n*16 + rl;
      const int ch  = q ^ ((row >> 1) & 3);
      bfr[n] = *(const bf16x8*)&Bs[slot][row*32 + ch*8];
    }
    #pragma unroll
    for (int m = 0; m < 5; m++){
      const int row = wm*160 + m*16 + rl;
      const int ch  = q ^ ((row >> 1) & 3);
      af[m] = *(const bf16x8*)&As[slot][row*32 + ch*8];
    }
    if (st){ stageA(s2, k2, 0); stageA(s2, k2, 1); stageA(s2, k2, 2); }
    asm volatile("s_waitcnt lgkmcnt(0)" ::: "memory");
    __builtin_amdgcn_sched_barrier(0);
    __builtin_amdgcn_s_setprio(1);
    #pragma unroll
    for (int m = 0; m < 5; m++)
      #pragma unroll
      for (int n = 0; n < 4; n++)
        acc[m][n] = __builtin_amdgcn_mfma_f32_16x16x32_bf16(af[m], bfr[n], acc[m][n], 0, 0, 0);
    __builtin_amdgcn_s_setprio(0);
    __builtin_amdgcn_sched_barrier(0);
    #pragma unroll
    for (int m = 0; m < 5; m++){
      const int row = wm*160 + (m+5)*16 + rl;
      const int ch  = q ^ ((row >> 1) & 3);
      af[m] = *(const bf16x8*)&As[slot][row*32 + ch*8];
    }
    if (st){ stageA(s2, k2, 3); stageA(s2, k2, 4); stageB(s2, k2); }
    asm volatile("s_waitcnt lgkmcnt(0)" ::: "memory");
    __builtin_amdgcn_sched_barrier(0);
    __builtin_amdgcn_s_setprio(1);
    #pragma unroll
    for (int m = 0; m < 5; m++)
      #pragma unroll
      for (int n = 0; n < 4; n++)
        acc[m+5][n] = __builtin_amdgcn_mfma_f32_16x16x32_bf16(af[m], bfr[n], acc[m+5][n], 0, 0, 0);
    __builtin_amdgcn_s_setprio(0);
  }

  const int head = (int)(n0 >> 8);           // BN=128 within one 256-col head
  // attention weight slice for this lane's 4 columns
  float asw[4], adw[4];
  #pragma unroll
  for (int n = 0; n < 4; n++){
    const int ch = (int)(n0 & 255) + wn*64 + n*16 + rl;
    asw[n] = as2[head*CCH + ch];
    adw[n] = ad2[head*CCH + ch];
  }
  #pragma unroll
  for (int m = 0; m < 10; m++)
    #pragma unroll
    for (int r = 0; r < 4; r++){
      const size_t row = m0 + wm*160 + m*16 + q*4 + r;
      float ps = 0.f, pd = 0.f;
      #pragma unroll
      for (int n = 0; n < 4; n++){
        const float cv = acc[m][n][r];
        ps = fmaf(cv, asw[n], ps);
        pd = fmaf(cv, adw[n], pd);
        const int ch = wn*64 + n*16 + rl + (int)(n0 & 255);
        Chm[((size_t)head*MPAD + row)*CCH + ch] = f2bf(cv);
      }
      #pragma unroll
      for (int d = 1; d < 16; d <<= 1){
        ps += __shfl_xor(ps, d);
        pd += __shfl_xor(pd, d);
      }
      if (rl == 0 && row < NN){
        atomicAdd(&als[row*NH + head], ps);
        atomicAdd(&ald[row*NH + head], pd);
      }
    }
}

// ---- layer-3 GEMM (128x128) + FUSED logits3 (heads=1).
__global__ __launch_bounds__(256, 2) void gemm_bt_kernel(
    const unsigned short* __restrict__ A,
    const unsigned short* __restrict__ Bt,
    unsigned short* __restrict__ C,
    const float* __restrict__ as3,            // [256]
    const float* __restrict__ ad3,            // [256]
    float* __restrict__ als,                  // [NN] (zeroed)
    float* __restrict__ ald,                  // [NN] (zeroed)
    int K, int Nn)
{
  __shared__ __align__(16) unsigned short As[2][128*32];
  __shared__ __align__(16) unsigned short Bs[2][128*32];
  const int tid  = threadIdx.x;
  const int wave = tid >> 6, lane = tid & 63;
  const int wr = wave >> 1, wc = wave & 1;
  const size_t m0 = (size_t)blockIdx.x * 128;
  const size_t n0 = (size_t)blockIdx.y * 128;

  const int l4 = lane >> 2;
  const int lc = lane & 3;

  f32x4 acc[4][4];
  #pragma unroll
  for (int i = 0; i < 4; i++)
    #pragma unroll
    for (int j = 0; j < 4; j++) acc[i][j] = (f32x4){0.f,0.f,0.f,0.f};

  auto stage = [&](int buf, int kt){
    const int k0 = kt << 5;
    #pragma unroll
    for (int half = 0; half < 2; ++half){
      const int rb  = (wave + half*4) * 16;
      const int row = rb + l4;
      const int kc  = lc ^ ((row >> 1) & 3);
      gload_lds16(A + ((m0 + row)*(size_t)K + k0 + kc*8), &As[buf][rb*32]);
    }
    #pragma unroll
    for (int half = 0; half < 2; ++half){
      const int rb  = (wave + half*4) * 16;
      const int row = rb + l4;
      const int kc  = lc ^ ((row >> 1) & 3);
      gload_lds16(Bt + ((n0 + row)*(size_t)K + k0 + kc*8), &Bs[buf][rb*32]);
    }
  };

  const int nt = K >> 5;
  stage(0, 0);
  __syncthreads();

  const int rl = lane & 15;
  const int q  = lane >> 4;

  int cur = 0;
  for (int t = 0; t < nt; ++t){
    if (t + 1 < nt) stage(cur ^ 1, t + 1);
    bf16x8 af[4], bfr[4];
    #pragma unroll
    for (int m = 0; m < 4; m++){
      int row = wr*64 + m*16 + rl;
      int ch  = q ^ ((row >> 1) & 3);
      af[m] = *(const bf16x8*)&As[cur][row*32 + ch*8];
    }
    #pragma unroll
    for (int n = 0; n < 4; n++){
      int row = wc*64 + n*16 + rl;
      int ch  = q ^ ((row >> 1) & 3);
      bfr[n] = *(const bf16x8*)&Bs[cur][row*32 + ch*8];
    }
    #pragma unroll
    for (int m = 0; m < 4; m++)
      #pragma unroll
      for (int n = 0; n < 4; n++)
        acc[m][n] = __builtin_amdgcn_mfma_f32_16x16x32_bf16(af[m], bfr[n], acc[m][n], 0, 0, 0);
    __syncthreads();
    cur ^= 1;
  }

  float asw[4], adw[4];
  #pragma unroll
  for (int n = 0; n < 4; n++){
    const int ch = (int)n0 + wc*64 + n*16 + rl;
    asw[n] = as3[ch];
    adw[n] = ad3[ch];
  }
  #pragma unroll
  for (int m = 0; m < 4; m++)
    #pragma unroll
    for (int r = 0; r < 4; r++){
      const size_t row = m0 + wr*64 + m*16 + q*4 + r;
      float ps = 0.f, pd = 0.f;
      #pragma unroll
      for (int n = 0; n < 4; n++){
        const float cv = acc[m][n][r];
        ps = fmaf(cv, asw[n], ps);
        pd = fmaf(cv, adw[n], pd);
        const size_t col = n0 + wc*64 + n*16 + rl;
        C[row*(size_t)Nn + col] = f2bf(cv);
      }
      #pragma unroll
      for (int d = 1; d < 16; d <<= 1){
        ps += __shfl_xor(ps, d);
        pd += __shfl_xor(pd, d);
      }
      if (rl == 0 && row < NN){
        atomicAdd(&als[row], ps);
        atomicAdd(&ald[row], pd);
      }
    }
}

// ---- wave-per-(v,head) segment softmax + aggregation + bias + ELU (R14 form)
template<int NHD>
__global__ __launch_bounds__(256) void aggw_kernel(
    const unsigned short* __restrict__ Hm,
    const int* __restrict__ off, const int* __restrict__ csrc,
    const float* __restrict__ als, const float* __restrict__ ald,
    const float* __restrict__ bias,
    unsigned short* __restrict__ actout,
    float* __restrict__ fout)
{
  const int wv = threadIdx.x >> 6, lane = threadIdx.x & 63;
  const int hl = lane >> 5;
  const int li = lane & 31;
  int v, h;
  if constexpr (NHD == 8){
    h = blockIdx.x & 7;
    v = (blockIdx.x >> 3) * 4 + wv;
  } else {
    h = 0;
    v = blockIdx.x * 4 + wv;
  }
  if (v >= NN) return;
  const int e0 = off[v], deg = off[v+1] - e0;
  const float aldv = ald[v*NHD + h];

  __shared__ float al_sh[4][64];
  __shared__ int   u_sh[4][64];

  float mloc = -1e30f;
  for (int i = lane; i < deg; i += 64){
    int u = csrc[e0 + i];
    float xe = als[u*NHD + h] + aldv;
    xe = xe > 0.f ? xe : 0.2f*xe;
    mloc = fmaxf(mloc, xe);
  }
  #pragma unroll
  for (int d = 1; d < 64; d <<= 1) mloc = fmaxf(mloc, __shfl_xor(mloc, d));
  float sloc = 0.f;
  for (int i = lane; i < deg; i += 64){
    int u = csrc[e0 + i];
    float xe = als[u*NHD + h] + aldv;
    xe = xe > 0.f ? xe : 0.2f*xe;
    sloc += __expf(xe - mloc);
  }
  #pragma unroll
  for (int d = 1; d < 64; d <<= 1) sloc += __shfl_xor(sloc, d);
  const float sinv = 1.f / (sloc + 1e-16f);

  const unsigned short* hB = Hm + (size_t)h*MPAD*CCH + li*8;
  float acc[8];
  #pragma unroll
  for (int k = 0; k < 8; k++) acc[k] = 0.f;

  auto edge_fma = [&](const uint4& w, float a){
    acc[0] = fmaf(a, bf2f((unsigned short)(w.x & 0xffff)), acc[0]);
    acc[1] = fmaf(a, bf2f((unsigned short)(w.x >> 16)),    acc[1]);
    acc[2] = fmaf(a, bf2f((unsigned short)(w.y & 0xffff)), acc[2]);
    acc[3] = fmaf(a, bf2f((unsigned short)(w.y >> 16)),    acc[3]);
    acc[4] = fmaf(a, bf2f((unsigned short)(w.z & 0xffff)), acc[4]);
    acc[5] = fmaf(a, bf2f((unsigned short)(w.z >> 16)),    acc[5]);
    acc[6] = fmaf(a, bf2f((unsigned short)(w.w & 0xffff)), acc[6]);
    acc[7] = fmaf(a, bf2f((unsigned short)(w.w >> 16)),    acc[7]);
  };

  for (int base = 0; base < deg; base += 64){
    const int nch = min(deg - base, 64);
    if (lane < nch){
      int u = csrc[e0 + base + lane];
      u_sh[wv][lane] = u;
      float xe = als[u*NHD + h] + aldv;
      xe = xe > 0.f ? xe : 0.2f*xe;
      al_sh[wv][lane] = __expf(xe - mloc) * sinv;
    }
    int j = 0;
    for (; j + 4 <= nch; j += 4){
      const int   ua = u_sh[wv][j + hl],     ub = u_sh[wv][j + 2 + hl];
      const float aa = al_sh[wv][j + hl],    ab = al_sh[wv][j + 2 + hl];
      uint4 wA = *(const uint4*)(hB + (size_t)ua*CCH);
      uint4 wB = *(const uint4*)(hB + (size_t)ub*CCH);
      edge_fma(wA, aa);
      edge_fma(wB, ab);
    }
    for (; j + 2 <= nch; j += 2){
      const int   ua = u_sh[wv][j + hl];
      const float aa = al_sh[wv][j + hl];
      uint4 wA = *(const uint4*)(hB + (size_t)ua*CCH);
      edge_fma(wA, aa);
    }
    if (j < nch && hl == 0){
      const int   ua = u_sh[wv][j];
      const float aa = al_sh[wv][j];
      uint4 wA = *(const uint4*)(hB + (size_t)ua*CCH);
      edge_fma(wA, aa);
    }
  }

  #pragma unroll
  for (int k = 0; k < 8; k++) acc[k] += __shfl_xor(acc[k], 32);

  if (hl == 0){
    const int c0 = h*CCH + li*8;
    float o[8];
    #pragma unroll
    for (int k = 0; k < 8; k++){
      o[k] = acc[k] + bias[c0 + k];
      o[k] = o[k] > 0.f ? o[k] : (__expf(o[k]) - 1.f);
    }
    if constexpr (NHD == 8){
      bf16x8 ov;
      #pragma unroll
      for (int k = 0; k < 8; k++) ov[k] = (short)f2bf(o[k]);
      *(bf16x8*)&actout[(size_t)v*F12 + c0] = ov;
    } else {
      float4 o0 = make_float4(o[0], o[1], o[2], o[3]);
      float4 o1 = make_float4(o[4], o[5], o[6], o[7]);
      *(float4*)(fout + (size_t)v*CCH + li*8)     = o0;
      *(float4*)(fout + (size_t)v*CCH + li*8 + 4) = o1;
    }
  }
}

extern "C" void kernel_launch(void* const* d_in, const int* in_sizes, int n_in,
                              void* d_out, int out_size, void* d_ws, size_t ws_size,
                              hipStream_t stream)
{
  const float* x   = (const float*)d_in[0];
  const int*   ei  = (const int*)d_in[1];
  const float* W1  = (const float*)d_in[2];
  const float* as1 = (const float*)d_in[3];
  const float* ad1 = (const float*)d_in[4];
  const float* b1  = (const float*)d_in[5];
  const float* W2  = (const float*)d_in[6];
  const float* as2 = (const float*)d_in[7];
  const float* ad2 = (const float*)d_in[8];
  const float* b2  = (const float*)d_in[9];
  const float* W3  = (const float*)d_in[10];
  const float* as3 = (const float*)d_in[11];
  const float* ad3 = (const float*)d_in[12];
  const float* b3  = (const float*)d_in[13];
  float* out = (float*)d_out;
  (void)in_sizes; (void)n_in; (void)out_size; (void)ws_size;

  char* p = (char*)d_ws;
  auto carve = [&](size_t bytes)->char* {
    char* r = p; p += (bytes + 255) & ~(size_t)255; return r;
  };
  unsigned short* actA = (unsigned short*)carve((size_t)MPAD*F12*2);
  unsigned short* hbuf = (unsigned short*)carve((size_t)MPAD*F12*2);  // head-major
  unsigned short* Wt1  = (unsigned short*)carve((size_t)F12*DIN*2);
  unsigned short* Wt2  = (unsigned short*)carve((size_t)F12*F12*2);
  unsigned short* Wt3  = (unsigned short*)carve((size_t)CCH*F12*2);
  float* als  = (float*)carve((size_t)NN*NH*4);
  float* ald  = (float*)carve((size_t)NN*NH*4);
  float* Wa1  = (float*)carve((size_t)64*16*4);
  int* deg    = (int*)carve((size_t)NN*4);
  int* cursor = (int*)carve((size_t)NN*4);
  int* off    = (int*)carve((size_t)(NN+1)*4);
  int* csrc   = (int*)carve((size_t)NE*4);
  unsigned short* Xa = hbuf;   // [MPAD][8][64] alias; dead before gemm_l2 writes hbuf

  const int* esrc = ei;
  const int* edst = ei + NE;

  // weight transposes
  transpose_cvt_kernel<<<dim3(DIN/32,  F12/32), 256, 0, stream>>>(W1, Wt1, DIN, F12);
  transpose_cvt_kernel<<<dim3(F12/32,  F12/32), 256, 0, stream>>>(W2, Wt2, F12, F12);
  transpose_cvt_kernel<<<dim3(F12/32,  CCH/32), 256, 0, stream>>>(W3, Wt3, F12, CCH);

  // CSR by dst
  hipMemsetAsync(deg,    0, (size_t)NN*4, stream);
  hipMemsetAsync(cursor, 0, (size_t)NN*4, stream);
  hist_kernel<<<(NE + 255)/256, 256, 0, stream>>>(edst, deg, NE);
  scan_kernel<<<1, 256, 0, stream>>>(deg, off, NN);
  scatter_kernel<<<(NE + 255)/256, 256, 0, stream>>>(esrc, edst, off, cursor, csrc, NE);

  // layer 1 (linearity restructure)
  wa1_kernel<<<4, 256, 0, stream>>>(W1, as1, ad1, Wa1);
  logits1_kernel<<<(NN*16 + 255)/256, 256, 0, stream>>>(x, Wa1, als, ald);
  hipMemsetAsync(Xa + (size_t)NN*512, 0, (size_t)(MPAD-NN)*512*2, stream);
  agg1_kernel<<<(NN + 3)/4, 256, 0, stream>>>(x, off, csrc, als, ald, Xa);
  gemm_l1_kernel<<<dim3(MPAD/128, NH), 256, 0, stream>>>(Xa, Wt1, b1, actA);

  // layer 2: zero logits, GEMM with fused logits, aggregate
  hipMemsetAsync(als, 0, (size_t)NN*NH*4, stream);
  hipMemsetAsync(ald, 0, (size_t)NN*NH*4, stream);
  gemm_l2_kernel<<<256, 512, 0, stream>>>(actA, Wt2, hbuf, as2, ad2, als, ald, F12);
  aggw_kernel<8><<<((NN + 3)/4)*8, 256, 0, stream>>>(hbuf, off, csrc, als, ald, b2, actA, nullptr);

  // layer 3: zero logits, GEMM with fused logits, aggregate
  hipMemsetAsync(als, 0, (size_t)NN*4, stream);
  hipMemsetAsync(ald, 0, (size_t)NN*4, stream);
  gemm_bt_kernel<<<dim3(MPAD/128, CCH/128), 256, 0, stream>>>(actA, Wt3, hbuf, as3, ad3, als, ald, F12, CCH);
  aggw_kernel<1><<<(NN + 3)/4, 256, 0, stream>>>(hbuf, off, csrc, als, ald, b3, nullptr, out);
}

// Round 17
// 322.611 us; speedup vs baseline: 1.1311x; 1.1311x over previous
//
#include <hip/hip_runtime.h>

// GAT 3-layer forward, MI355X gfx950.
// R17: fix R16's partial-slot collision -- each (row,head) has FOUR partial
// producers (tile-half x wave-N), so partials are [4][MPAD*NH] with slot =
// ch2*2 + wn (L2) / ch2*2 + wc (L3); combine sums 4. Rest identical to R16.

typedef __attribute__((ext_vector_type(8))) short bf16x8;
typedef __attribute__((ext_vector_type(4))) float f32x4;

#define DEVINL __device__ __forceinline__

static constexpr int NN   = 10000;
static constexpr int NE   = 160000;
static constexpr int MPAD = 10240;   // 16*640, 80*128
static constexpr int DIN  = 64;
static constexpr int CCH  = 256;
static constexpr int NH   = 8;
static constexpr int F12  = 2048;    // NH * CCH
static constexpr int PSTR = MPAD*NH; // partials slot stride

DEVINL unsigned short f2bf(float x){
  unsigned u = __float_as_uint(x);
  u += 0x7fffu + ((u >> 16) & 1u);           // RNE
  return (unsigned short)(u >> 16);
}
DEVINL float bf2f(unsigned short h){ return __uint_as_float(((unsigned)h) << 16); }

DEVINL void gload_lds16(const unsigned short* g, unsigned short* lds){
  __builtin_amdgcn_global_load_lds(
      (__attribute__((address_space(1))) unsigned int*)(g),
      (__attribute__((address_space(3))) unsigned int*)(lds), 16, 0, 0);
}

// ---- W [K][Nn] f32 -> Wt [Nn][K] bf16
__global__ __launch_bounds__(256) void transpose_cvt_kernel(const float* __restrict__ W,
                                                            unsigned short* __restrict__ Wt,
                                                            int K, int Nn){
  __shared__ float tile[32][33];
  int k0 = blockIdx.x*32, n0 = blockIdx.y*32;
  int tx = threadIdx.x & 31, ty = threadIdx.x >> 5;
  #pragma unroll
  for (int r = ty; r < 32; r += 8) tile[r][tx] = W[(size_t)(k0+r)*Nn + n0 + tx];
  __syncthreads();
  #pragma unroll
  for (int r = ty; r < 32; r += 8) Wt[(size_t)(n0+r)*K + k0 + tx] = f2bf(tile[tx][r]);
}

// ---- CSR build
__global__ __launch_bounds__(256) void hist_kernel(const int* __restrict__ dst,
                                                   int* __restrict__ deg, int E_){
  int i = blockIdx.x*256 + threadIdx.x;
  if (i < E_) atomicAdd(&deg[dst[i]], 1);
}

__global__ __launch_bounds__(256) void scan_kernel(const int* __restrict__ deg,
                                                   int* __restrict__ off, int n){
  const int CH = (n + 255) / 256;
  int t = threadIdx.x;
  int lo = t*CH, hi = min(lo + CH, n);
  int s = 0;
  for (int i = lo; i < hi; i++) s += deg[i];
  __shared__ int ws[256];
  ws[t] = s;
  __syncthreads();
  for (int d = 1; d < 256; d <<= 1){
    int v = (t >= d) ? ws[t-d] : 0;
    __syncthreads();
    ws[t] += v;
    __syncthreads();
  }
  int run = ws[t] - s;
  for (int i = lo; i < hi; i++){ off[i] = run; run += deg[i]; }
  if (t == 255) off[n] = ws[255];
}

__global__ __launch_bounds__(256) void scatter_kernel(const int* __restrict__ src,
                                                      const int* __restrict__ dst,
                                                      const int* __restrict__ off,
                                                      int* __restrict__ cursor,
                                                      int* __restrict__ csrc, int E_){
  int i = blockIdx.x*256 + threadIdx.x;
  if (i >= E_) return;
  int d = dst[i];
  int pI = atomicAdd(&cursor[d], 1);
  csrc[off[d] + pI] = src[i];
}

// ---- Wa1[c][i] = sum_j W1[c][h*256+j] * a1{s,d}[h][j]
__global__ __launch_bounds__(256) void wa1_kernel(const float* __restrict__ W1,
                                                  const float* __restrict__ a1s,
                                                  const float* __restrict__ a1d,
                                                  float* __restrict__ Wa1){
  int t = blockIdx.x*256 + threadIdx.x;
  if (t >= 64*16) return;
  int c = t >> 4, i = t & 15;
  int h = i & 7;
  const float* a = (i < 8) ? a1s : a1d;
  float s = 0.f;
  #pragma unroll 8
  for (int j = 0; j < 256; j++) s = fmaf(W1[(size_t)c*F12 + h*256 + j], a[h*256 + j], s);
  Wa1[c*16 + i] = s;
}

// ---- layer-1 logits straight from x
__global__ __launch_bounds__(256) void logits1_kernel(const float* __restrict__ x,
                                                      const float* __restrict__ Wa1,
                                                      float* __restrict__ als,
                                                      float* __restrict__ ald){
  __shared__ float wa[64*16];
  for (int i = threadIdx.x; i < 64*16; i += 256) wa[i] = Wa1[i];
  __syncthreads();
  int gid = blockIdx.x*256 + threadIdx.x;
  int v = gid >> 4, i = gid & 15;
  if (v >= NN) return;
  float s = 0.f;
  #pragma unroll
  for (int c = 0; c < 64; c++) s = fmaf(x[(size_t)v*64 + c], wa[c*16 + i], s);
  if (i < 8) als[v*8 + i] = s;
  else       ald[v*8 + (i - 8)] = s;
}

// ---- combine logits partials (4 slots)
__global__ __launch_bounds__(256) void combine_kernel(const float* __restrict__ pls,
                                                      const float* __restrict__ pld,
                                                      float* __restrict__ als,
                                                      float* __restrict__ ald,
                                                      int count){
  int i = blockIdx.x*256 + threadIdx.x;
  if (i >= count) return;
  als[i] = (pls[i] + pls[PSTR + i]) + (pls[2*PSTR + i] + pls[3*PSTR + i]);
  ald[i] = (pld[i] + pld[PSTR + i]) + (pld[2*PSTR + i] + pld[3*PSTR + i]);
}

// ---- layer-1 aggregation (R13): lane=(edge_slot,head) softmax, LDS alpha stage
__global__ __launch_bounds__(256) void agg1_kernel(const float* __restrict__ x,
                                                   const int* __restrict__ off,
                                                   const int* __restrict__ csrc,
                                                   const float* __restrict__ als,
                                                   const float* __restrict__ ald,
                                                   unsigned short* __restrict__ Xa){
  const int wv = threadIdx.x >> 6, lane = threadIdx.x & 63;
  const int v = blockIdx.x*4 + wv;
  if (v >= NN) return;
  const int e0 = off[v], deg = off[v+1] - e0;
  const int h  = lane & 7;
  const int es = lane >> 3;

  __shared__ float al_sh[4][64];
  __shared__ int   u_sh[4][8];

  const float aldv = ald[v*8 + h];

  float m = -1e30f, s = 0.f;
  for (int i = es; i < deg; i += 8){
    int u = csrc[e0 + i];
    float xe = als[u*8 + h] + aldv;
    xe = xe > 0.f ? xe : 0.2f*xe;
    float nm = fmaxf(m, xe);
    s = s*__expf(m - nm) + __expf(xe - nm);
    m = nm;
  }
  #pragma unroll
  for (int d = 8; d < 64; d <<= 1){
    float mo = __shfl_xor(m, d);
    float so = __shfl_xor(s, d);
    float nm = fmaxf(m, mo);
    s = s*__expf(m - nm) + so*__expf(mo - nm);
    m = nm;
  }
  const float sinv = 1.f / (s + 1e-16f);

  float acc[8];
  #pragma unroll
  for (int hh = 0; hh < 8; hh++) acc[hh] = 0.f;

  const int nfull = deg & ~7;
  for (int base = 0; base < nfull; base += 8){
    int u = csrc[e0 + base + es];
    if (h == 0) u_sh[wv][es] = u;
    float xe = als[u*8 + h] + aldv;
    xe = xe > 0.f ? xe : 0.2f*xe;
    al_sh[wv][es*8 + h] = __expf(xe - m) * sinv;
    #pragma unroll
    for (int j = 0; j < 8; j++){
      float xv = x[(size_t)u_sh[wv][j]*64 + lane];
      #pragma unroll
      for (int hh = 0; hh < 8; hh++)
        acc[hh] = fmaf(al_sh[wv][j*8 + hh], xv, acc[hh]);
    }
  }
  if (nfull < deg){
    const int nch = deg - nfull;
    if (es < nch){
      int u = csrc[e0 + nfull + es];
      if (h == 0) u_sh[wv][es] = u;
      float xe = als[u*8 + h] + aldv;
      xe = xe > 0.f ? xe : 0.2f*xe;
      al_sh[wv][es*8 + h] = __expf(xe - m) * sinv;
    }
    for (int j = 0; j < nch; j++){
      float xv = x[(size_t)u_sh[wv][j]*64 + lane];
      #pragma unroll
      for (int hh = 0; hh < 8; hh++)
        acc[hh] = fmaf(al_sh[wv][j*8 + hh], xv, acc[hh]);
    }
  }

  #pragma unroll
  for (int hh = 0; hh < 8; hh++)
    Xa[(size_t)v*512 + hh*64 + lane] = f2bf(acc[hh]);
}

// ---- layer-1 GEMM per head with fused bias+ELU
__global__ __launch_bounds__(256) void gemm_l1_kernel(
    const unsigned short* __restrict__ Xa,    // [MPAD][8][64]
    const unsigned short* __restrict__ Wt1,   // [2048][64]
    const float* __restrict__ b1,
    unsigned short* __restrict__ actA)        // [MPAD][2048]
{
  __shared__ __align__(16) unsigned short As[2][128*32];
  __shared__ __align__(16) unsigned short Bs[2][256*32];
  const int wave = threadIdx.x >> 6, lane = threadIdx.x & 63;
  const int wm = wave >> 1, wn = wave & 1;
  const size_t m0 = (size_t)blockIdx.x * 128;
  const int h = blockIdx.y;
  const int lr = lane >> 2, l3 = lane & 3;

  #pragma unroll
  for (int sB = 0; sB < 2; sB++){
    #pragma unroll
    for (int j = 0; j < 2; j++){
      int rb = (wave*2 + j)*16;
      int row = rb + lr;
      int kc = l3 ^ ((row >> 1) & 3);
      gload_lds16(Xa + (m0 + row)*512 + h*64 + sB*32 + kc*8, &As[sB][rb*32]);
    }
    #pragma unroll
    for (int j = 0; j < 4; j++){
      int rb = (wave*4 + j)*16;
      int row = rb + lr;
      int kc = l3 ^ ((row >> 1) & 3);
      gload_lds16(Wt1 + (size_t)(h*256 + row)*64 + sB*32 + kc*8, &Bs[sB][rb*32]);
    }
  }
  asm volatile("s_waitcnt vmcnt(0)" ::: "memory");
  __syncthreads();

  f32x4 acc[4][8];
  #pragma unroll
  for (int i = 0; i < 4; i++)
    #pragma unroll
    for (int j = 0; j < 8; j++) acc[i][j] = (f32x4){0.f,0.f,0.f,0.f};

  const int rl = lane & 15, q = lane >> 4;
  #pragma unroll
  for (int sB = 0; sB < 2; sB++){
    bf16x8 af[4], bfr[8];
    #pragma unroll
    for (int mm = 0; mm < 4; mm++){
      int row = wm*64 + mm*16 + rl;
      int ch = q ^ ((row >> 1) & 3);
      af[mm] = *(const bf16x8*)&As[sB][row*32 + ch*8];
    }
    #pragma unroll
    for (int n = 0; n < 8; n++){
      int row = wn*128 + n*16 + rl;
      int ch = q ^ ((row >> 1) & 3);
      bfr[n] = *(const bf16x8*)&Bs[sB][row*32 + ch*8];
    }
    #pragma unroll
    for (int mm = 0; mm < 4; mm++)
      #pragma unroll
      for (int n = 0; n < 8; n++)
        acc[mm][n] = __builtin_amdgcn_mfma_f32_16x16x32_bf16(af[mm], bfr[n], acc[mm][n], 0, 0, 0);
  }

  #pragma unroll
  for (int mm = 0; mm < 4; mm++)
    #pragma unroll
    for (int n = 0; n < 8; n++)
      #pragma unroll
      for (int r = 0; r < 4; r++){
        size_t row = m0 + wm*64 + mm*16 + q*4 + r;
        int col = wn*128 + n*16 + rl;
        float o = acc[mm][n][r] + b1[h*256 + col];
        o = o > 0.f ? o : (__expf(o) - 1.f);
        actA[row*F12 + h*256 + col] = f2bf(o);
      }
}

// ---- layer-2 GEMM (R11 config) + fused logits partials (plain stores).
// Partial slot = ch2*2 + wn (4 producers per (row,head)).
__global__ __launch_bounds__(512, 1) void gemm_l2_kernel(
    const unsigned short* __restrict__ A,
    const unsigned short* __restrict__ Bt,
    unsigned short* __restrict__ Chm,         // [8][MPAD][256]
    const float* __restrict__ as2,            // [8][256]
    const float* __restrict__ ad2,            // [8][256]
    float* __restrict__ pls,                  // [4][MPAD*8]
    float* __restrict__ pld,                  // [4][MPAD*8]
    int K)
{
  __shared__ __align__(16) unsigned short As[3][640*32];   // 3 x 40KB
  __shared__ __align__(16) unsigned short Bs[3][128*32];   // 3 x 8KB

  const int tid  = threadIdx.x;
  const int wave = tid >> 6, lane = tid & 63;
  const int wm = wave >> 1, wn = wave & 1;          // 4Mx2N, per-wave 160x64

  const int orig = blockIdx.x;
  const int wg   = (orig & 7) * 32 + (orig >> 3);
  const size_t m0 = (size_t)(wg >> 4) * 640;
  const size_t n0 = (size_t)(wg & 15) * 128;

  f32x4 acc[10][4];
  #pragma unroll
  for (int i = 0; i < 10; i++)
    #pragma unroll
    for (int j = 0; j < 4; j++) acc[i][j] = (f32x4){0.f,0.f,0.f,0.f};

  const int lr = lane >> 2;
  const int l3 = lane & 3;

  auto stageA = [&](int slot, int k0, int j){
    const int rb  = (wave*5 + j) * 16;
    const int row = rb + lr;
    const int kc  = l3 ^ ((row >> 1) & 3);
    gload_lds16(A + (m0 + row)*(size_t)K + k0 + kc*8, &As[slot][rb*32]);
  };
  auto stageB = [&](int slot, int k0){
    const int rb  = wave * 16;
    const int row = rb + lr;
    const int kc  = l3 ^ ((row >> 1) & 3);
    gload_lds16(Bt + (n0 + row)*(size_t)K + k0 + kc*8, &Bs[slot][rb*32]);
  };
  auto stageTile = [&](int T){
    const int slot = T % 3, k0 = T << 5;
    #pragma unroll
    for (int j = 0; j < 5; j++) stageA(slot, k0, j);
    stageB(slot, k0);
  };

  const int nt = K >> 5;            // 64
  stageTile(0);
  stageTile(1);

  const int rl = lane & 15;
  const int q  = lane >> 4;

  for (int T = 0; T < nt; ++T){
    if (T + 1 < nt) asm volatile("s_waitcnt vmcnt(6)" ::: "memory");
    else            asm volatile("s_waitcnt vmcnt(0)" ::: "memory");
    __builtin_amdgcn_s_barrier();

    const int slot = T % 3;
    const bool st  = (T + 2 < nt);
    const int s2   = (T + 2) % 3;
    const int k2   = (T + 2) << 5;

    bf16x8 bfr[4], af[5];
    #pragma unroll
    for (int n = 0; n < 4; n++){
      const int row = wn*64 + n*16 + rl;
      const int ch  = q ^ ((row >> 1) & 3);
      bfr[n] = *(const bf16x8*)&Bs[slot][row*32 + ch*8];
    }
    #pragma unroll
    for (int m = 0; m < 5; m++){
      const int row = wm*160 + m*16 + rl;
      const int ch  = q ^ ((row >> 1) & 3);
      af[m] = *(const bf16x8*)&As[slot][row*32 + ch*8];
    }
    if (st){ stageA(s2, k2, 0); stageA(s2, k2, 1); stageA(s2, k2, 2); }
    asm volatile("s_waitcnt lgkmcnt(0)" ::: "memory");
    __builtin_amdgcn_sched_barrier(0);
    __builtin_amdgcn_s_setprio(1);
    #pragma unroll
    for (int m = 0; m < 5; m++)
      #pragma unroll
      for (int n = 0; n < 4; n++)
        acc[m][n] = __builtin_amdgcn_mfma_f32_16x16x32_bf16(af[m], bfr[n], acc[m][n], 0, 0, 0);
    __builtin_amdgcn_s_setprio(0);
    __builtin_amdgcn_sched_barrier(0);
    #pragma unroll
    for (int m = 0; m < 5; m++){
      const int row = wm*160 + (m+5)*16 + rl;
      const int ch  = q ^ ((row >> 1) & 3);
      af[m] = *(const bf16x8*)&As[slot][row*32 + ch*8];
    }
    if (st){ stageA(s2, k2, 3); stageA(s2, k2, 4); stageB(s2, k2); }
    asm volatile("s_waitcnt lgkmcnt(0)" ::: "memory");
    __builtin_amdgcn_sched_barrier(0);
    __builtin_amdgcn_s_setprio(1);
    #pragma unroll
    for (int m = 0; m < 5; m++)
      #pragma unroll
      for (int n = 0; n < 4; n++)
        acc[m+5][n] = __builtin_amdgcn_mfma_f32_16x16x32_bf16(af[m], bfr[n], acc[m+5][n], 0, 0, 0);
    __builtin_amdgcn_s_setprio(0);
  }

  const int head = (int)(n0 >> 8);           // BN=128 within one 256-col head
  const int pslot = (((int)(n0 >> 7) & 1) << 1) | wn;   // 4 producers/(row,head)
  float asw[4], adw[4];
  #pragma unroll
  for (int n = 0; n < 4; n++){
    const int ch = (int)(n0 & 255) + wn*64 + n*16 + rl;
    asw[n] = as2[head*CCH + ch];
    adw[n] = ad2[head*CCH + ch];
  }
  #pragma unroll
  for (int m = 0; m < 10; m++)
    #pragma unroll
    for (int r = 0; r < 4; r++){
      const size_t row = m0 + wm*160 + m*16 + q*4 + r;
      float ps = 0.f, pd = 0.f;
      #pragma unroll
      for (int n = 0; n < 4; n++){
        const float cv = acc[m][n][r];
        ps = fmaf(cv, asw[n], ps);
        pd = fmaf(cv, adw[n], pd);
        const int ch = wn*64 + n*16 + rl + (int)(n0 & 255);
        Chm[((size_t)head*MPAD + row)*CCH + ch] = f2bf(cv);
      }
      #pragma unroll
      for (int d = 1; d < 16; d <<= 1){
        ps += __shfl_xor(ps, d);
        pd += __shfl_xor(pd, d);
      }
      if (rl == 0){
        pls[(size_t)pslot*PSTR + row*NH + head] = ps;
        pld[(size_t)pslot*PSTR + row*NH + head] = pd;
      }
    }
}

// ---- layer-3 GEMM (128x128) + fused logits partials (slot = ch2*2+wc).
__global__ __launch_bounds__(256, 2) void gemm_bt_kernel(
    const unsigned short* __restrict__ A,
    const unsigned short* __restrict__ Bt,
    unsigned short* __restrict__ C,
    const float* __restrict__ as3,            // [256]
    const float* __restrict__ ad3,            // [256]
    float* __restrict__ pls,                  // [4][MPAD*8] (row-indexed)
    float* __restrict__ pld,
    int K, int Nn)
{
  __shared__ __align__(16) unsigned short As[2][128*32];
  __shared__ __align__(16) unsigned short Bs[2][128*32];
  const int tid  = threadIdx.x;
  const int wave = tid >> 6, lane = tid & 63;
  const int wr = wave >> 1, wc = wave & 1;
  const size_t m0 = (size_t)blockIdx.x * 128;
  const size_t n0 = (size_t)blockIdx.y * 128;

  const int l4 = lane >> 2;
  const int lc = lane & 3;

  f32x4 acc[4][4];
  #pragma unroll
  for (int i = 0; i < 4; i++)
    #pragma unroll
    for (int j = 0; j < 4; j++) acc[i][j] = (f32x4){0.f,0.f,0.f,0.f};

  auto stage = [&](int buf, int kt){
    const int k0 = kt << 5;
    #pragma unroll
    for (int half = 0; half < 2; ++half){
      const int rb  = (wave + half*4) * 16;
      const int row = rb + l4;
      const int kc  = lc ^ ((row >> 1) & 3);
      gload_lds16(A + ((m0 + row)*(size_t)K + k0 + kc*8), &As[buf][rb*32]);
    }
    #pragma unroll
    for (int half = 0; half < 2; ++half){
      const int rb  = (wave + half*4) * 16;
      const int row = rb + l4;
      const int kc  = lc ^ ((row >> 1) & 3);
      gload_lds16(Bt + ((n0 + row)*(size_t)K + k0 + kc*8), &Bs[buf][rb*32]);
    }
  };

  const int nt = K >> 5;
  stage(0, 0);
  __syncthreads();

  const int rl = lane & 15;
  const int q  = lane >> 4;

  int cur = 0;
  for (int t = 0; t < nt; ++t){
    if (t + 1 < nt) stage(cur ^ 1, t + 1);
    bf16x8 af[4], bfr[4];
    #pragma unroll
    for (int m = 0; m < 4; m++){
      int row = wr*64 + m*16 + rl;
      int ch  = q ^ ((row >> 1) & 3);
      af[m] = *(const bf16x8*)&As[cur][row*32 + ch*8];
    }
    #pragma unroll
    for (int n = 0; n < 4; n++){
      int row = wc*64 + n*16 + rl;
      int ch  = q ^ ((row >> 1) & 3);
      bfr[n] = *(const bf16x8*)&Bs[cur][row*32 + ch*8];
    }
    #pragma unroll
    for (int m = 0; m < 4; m++)
      #pragma unroll
      for (int n = 0; n < 4; n++)
        acc[m][n] = __builtin_amdgcn_mfma_f32_16x16x32_bf16(af[m], bfr[n], acc[m][n], 0, 0, 0);
    __syncthreads();
    cur ^= 1;
  }

  float asw[4], adw[4];
  #pragma unroll
  for (int n = 0; n < 4; n++){
    const int ch = (int)n0 + wc*64 + n*16 + rl;
    asw[n] = as3[ch];
    adw[n] = ad3[ch];
  }
  const int pslot = (((int)(n0 >> 7)) << 1) | wc;
  #pragma unroll
  for (int m = 0; m < 4; m++)
    #pragma unroll
    for (int r = 0; r < 4; r++){
      const size_t row = m0 + wr*64 + m*16 + q*4 + r;
      float ps = 0.f, pd = 0.f;
      #pragma unroll
      for (int n = 0; n < 4; n++){
        const float cv = acc[m][n][r];
        ps = fmaf(cv, asw[n], ps);
        pd = fmaf(cv, adw[n], pd);
        const size_t col = n0 + wc*64 + n*16 + rl;
        C[row*(size_t)Nn + col] = f2bf(cv);
      }
      #pragma unroll
      for (int d = 1; d < 16; d <<= 1){
        ps += __shfl_xor(ps, d);
        pd += __shfl_xor(pd, d);
      }
      if (rl == 0){
        pls[(size_t)pslot*PSTR + row] = ps;
        pld[(size_t)pslot*PSTR + row] = pd;
      }
    }
}

// ---- wave-per-(v,head) segment softmax + aggregation + bias + ELU (R14 form)
template<int NHD>
__global__ __launch_bounds__(256) void aggw_kernel(
    const unsigned short* __restrict__ Hm,
    const int* __restrict__ off, const int* __restrict__ csrc,
    const float* __restrict__ als, const float* __restrict__ ald,
    const float* __restrict__ bias,
    unsigned short* __restrict__ actout,
    float* __restrict__ fout)
{
  const int wv = threadIdx.x >> 6, lane = threadIdx.x & 63;
  const int hl = lane >> 5;
  const int li = lane & 31;
  int v, h;
  if constexpr (NHD == 8){
    h = blockIdx.x & 7;
    v = (blockIdx.x >> 3) * 4 + wv;
  } else {
    h = 0;
    v = blockIdx.x * 4 + wv;
  }
  if (v >= NN) return;
  const int e0 = off[v], deg = off[v+1] - e0;
  const float aldv = ald[v*NHD + h];

  __shared__ float al_sh[4][64];
  __shared__ int   u_sh[4][64];

  float mloc = -1e30f;
  for (int i = lane; i < deg; i += 64){
    int u = csrc[e0 + i];
    float xe = als[u*NHD + h] + aldv;
    xe = xe > 0.f ? xe : 0.2f*xe;
    mloc = fmaxf(mloc, xe);
  }
  #pragma unroll
  for (int d = 1; d < 64; d <<= 1) mloc = fmaxf(mloc, __shfl_xor(mloc, d));
  float sloc = 0.f;
  for (int i = lane; i < deg; i += 64){
    int u = csrc[e0 + i];
    float xe = als[u*NHD + h] + aldv;
    xe = xe > 0.f ? xe : 0.2f*xe;
    sloc += __expf(xe - mloc);
  }
  #pragma unroll
  for (int d = 1; d < 64; d <<= 1) sloc += __shfl_xor(sloc, d);
  const float sinv = 1.f / (sloc + 1e-16f);

  const unsigned short* hB = Hm + (size_t)h*MPAD*CCH + li*8;
  float acc[8];
  #pragma unroll
  for (int k = 0; k < 8; k++) acc[k] = 0.f;

  auto edge_fma = [&](const uint4& w, float a){
    acc[0] = fmaf(a, bf2f((unsigned short)(w.x & 0xffff)), acc[0]);
    acc[1] = fmaf(a, bf2f((unsigned short)(w.x >> 16)),    acc[1]);
    acc[2] = fmaf(a, bf2f((unsigned short)(w.y & 0xffff)), acc[2]);
    acc[3] = fmaf(a, bf2f((unsigned short)(w.y >> 16)),    acc[3]);
    acc[4] = fmaf(a, bf2f((unsigned short)(w.z & 0xffff)), acc[4]);
    acc[5] = fmaf(a, bf2f((unsigned short)(w.z >> 16)),    acc[5]);
    acc[6] = fmaf(a, bf2f((unsigned short)(w.w & 0xffff)), acc[6]);
    acc[7] = fmaf(a, bf2f((unsigned short)(w.w >> 16)),    acc[7]);
  };

  for (int base = 0; base < deg; base += 64){
    const int nch = min(deg - base, 64);
    if (lane < nch){
      int u = csrc[e0 + base + lane];
      u_sh[wv][lane] = u;
      float xe = als[u*NHD + h] + aldv;
      xe = xe > 0.f ? xe : 0.2f*xe;
      al_sh[wv][lane] = __expf(xe - mloc) * sinv;
    }
    int j = 0;
    for (; j + 4 <= nch; j += 4){
      const int   ua = u_sh[wv][j + hl],     ub = u_sh[wv][j + 2 + hl];
      const float aa = al_sh[wv][j + hl],    ab = al_sh[wv][j + 2 + hl];
      uint4 wA = *(const uint4*)(hB + (size_t)ua*CCH);
      uint4 wB = *(const uint4*)(hB + (size_t)ub*CCH);
      edge_fma(wA, aa);
      edge_fma(wB, ab);
    }
    for (; j + 2 <= nch; j += 2){
      const int   ua = u_sh[wv][j + hl];
      const float aa = al_sh[wv][j + hl];
      uint4 wA = *(const uint4*)(hB + (size_t)ua*CCH);
      edge_fma(wA, aa);
    }
    if (j < nch && hl == 0){
      const int   ua = u_sh[wv][j];
      const float aa = al_sh[wv][j];
      uint4 wA = *(const uint4*)(hB + (size_t)ua*CCH);
      edge_fma(wA, aa);
    }
  }

  #pragma unroll
  for (int k = 0; k < 8; k++) acc[k] += __shfl_xor(acc[k], 32);

  if (hl == 0){
    const int c0 = h*CCH + li*8;
    float o[8];
    #pragma unroll
    for (int k = 0; k < 8; k++){
      o[k] = acc[k] + bias[c0 + k];
      o[k] = o[k] > 0.f ? o[k] : (__expf(o[k]) - 1.f);
    }
    if constexpr (NHD == 8){
      bf16x8 ov;
      #pragma unroll
      for (int k = 0; k < 8; k++) ov[k] = (short)f2bf(o[k]);
      *(bf16x8*)&actout[(size_t)v*F12 + c0] = ov;
    } else {
      float4 o0 = make_float4(o[0], o[1], o[2], o[3]);
      float4 o1 = make_float4(o[4], o[5], o[6], o[7]);
      *(float4*)(fout + (size_t)v*CCH + li*8)     = o0;
      *(float4*)(fout + (size_t)v*CCH + li*8 + 4) = o1;
    }
  }
}

extern "C" void kernel_launch(void* const* d_in, const int* in_sizes, int n_in,
                              void* d_out, int out_size, void* d_ws, size_t ws_size,
                              hipStream_t stream)
{
  const float* x   = (const float*)d_in[0];
  const int*   ei  = (const int*)d_in[1];
  const float* W1  = (const float*)d_in[2];
  const float* as1 = (const float*)d_in[3];
  const float* ad1 = (const float*)d_in[4];
  const float* b1  = (const float*)d_in[5];
  const float* W2  = (const float*)d_in[6];
  const float* as2 = (const float*)d_in[7];
  const float* ad2 = (const float*)d_in[8];
  const float* b2  = (const float*)d_in[9];
  const float* W3  = (const float*)d_in[10];
  const float* as3 = (const float*)d_in[11];
  const float* ad3 = (const float*)d_in[12];
  const float* b3  = (const float*)d_in[13];
  float* out = (float*)d_out;
  (void)in_sizes; (void)n_in; (void)out_size; (void)ws_size;

  char* p = (char*)d_ws;
  auto carve = [&](size_t bytes)->char* {
    char* r = p; p += (bytes + 255) & ~(size_t)255; return r;
  };
  unsigned short* actA = (unsigned short*)carve((size_t)MPAD*F12*2);
  unsigned short* hbuf = (unsigned short*)carve((size_t)MPAD*F12*2);  // head-major
  unsigned short* Wt1  = (unsigned short*)carve((size_t)F12*DIN*2);
  unsigned short* Wt2  = (unsigned short*)carve((size_t)F12*F12*2);
  unsigned short* Wt3  = (unsigned short*)carve((size_t)CCH*F12*2);
  float* als  = (float*)carve((size_t)NN*NH*4);
  float* ald  = (float*)carve((size_t)NN*NH*4);
  float* pls  = (float*)carve((size_t)4*PSTR*4);
  float* pld  = (float*)carve((size_t)4*PSTR*4);
  float* Wa1  = (float*)carve((size_t)64*16*4);
  int* deg    = (int*)carve((size_t)2*NN*4);      // deg + cursor contiguous
  int* cursor = deg + NN;
  int* off    = (int*)carve((size_t)(NN+1)*4);
  int* csrc   = (int*)carve((size_t)NE*4);
  unsigned short* Xa = hbuf;   // [MPAD][8][64] alias; dead before gemm_l2 writes hbuf

  const int* esrc = ei;
  const int* edst = ei + NE;

  // weight transposes
  transpose_cvt_kernel<<<dim3(DIN/32,  F12/32), 256, 0, stream>>>(W1, Wt1, DIN, F12);
  transpose_cvt_kernel<<<dim3(F12/32,  F12/32), 256, 0, stream>>>(W2, Wt2, F12, F12);
  transpose_cvt_kernel<<<dim3(F12/32,  CCH/32), 256, 0, stream>>>(W3, Wt3, F12, CCH);

  // CSR by dst (deg+cursor zeroed in one memset)
  hipMemsetAsync(deg, 0, (size_t)2*NN*4, stream);
  hist_kernel<<<(NE + 255)/256, 256, 0, stream>>>(edst, deg, NE);
  scan_kernel<<<1, 256, 0, stream>>>(deg, off, NN);
  scatter_kernel<<<(NE + 255)/256, 256, 0, stream>>>(esrc, edst, off, cursor, csrc, NE);

  // layer 1 (linearity restructure)
  wa1_kernel<<<4, 256, 0, stream>>>(W1, as1, ad1, Wa1);
  logits1_kernel<<<(NN*16 + 255)/256, 256, 0, stream>>>(x, Wa1, als, ald);
  hipMemsetAsync(Xa + (size_t)NN*512, 0, (size_t)(MPAD-NN)*512*2, stream);
  agg1_kernel<<<(NN + 3)/4, 256, 0, stream>>>(x, off, csrc, als, ald, Xa);
  gemm_l1_kernel<<<dim3(MPAD/128, NH), 256, 0, stream>>>(Xa, Wt1, b1, actA);

  // layer 2: GEMM with fused logits partials -> combine -> aggregate
  gemm_l2_kernel<<<256, 512, 0, stream>>>(actA, Wt2, hbuf, as2, ad2, pls, pld, F12);
  combine_kernel<<<(NN*NH + 255)/256, 256, 0, stream>>>(pls, pld, als, ald, NN*NH);
  aggw_kernel<8><<<((NN + 3)/4)*8, 256, 0, stream>>>(hbuf, off, csrc, als, ald, b2, actA, nullptr);

  // layer 3: GEMM with fused logits partials -> combine -> aggregate
  gemm_bt_kernel<<<dim3(MPAD/128, CCH/128), 256, 0, stream>>>(actA, Wt3, hbuf, as3, ad3, pls, pld, F12, CCH);
  combine_kernel<<<(NN + 255)/256, 256, 0, stream>>>(pls, pld, als, ald, NN);
  aggw_kernel<1><<<(NN + 3)/4, 256, 0, stream>>>(hbuf, off, csrc, als, ald, b3, nullptr, out);
}

// Round 18
// 314.916 us; speedup vs baseline: 1.1588x; 1.0244x over previous
//
#include <hip/hip_runtime.h>

// GAT 3-layer forward, MI355X gfx950.
// R18: layer-3 GEMM retiled BM=160xBN=128 -> 128 blocks x 2/CU = all 256 CUs
// busy (old 128x128 grid left 96 CUs idle). Role-split staging, counted
// per-role vmcnt, fused logits partials. Rest frozen from R17.

typedef __attribute__((ext_vector_type(8))) short bf16x8;
typedef __attribute__((ext_vector_type(4))) float f32x4;

#define DEVINL __device__ __forceinline__

static constexpr int NN   = 10000;
static constexpr int NE   = 160000;
static constexpr int MPAD = 10240;   // 16*640, 64*160, 80*128
static constexpr int DIN  = 64;
static constexpr int CCH  = 256;
static constexpr int NH   = 8;
static constexpr int F12  = 2048;    // NH * CCH
static constexpr int PSTR = MPAD*NH; // partials slot stride

DEVINL unsigned short f2bf(float x){
  unsigned u = __float_as_uint(x);
  u += 0x7fffu + ((u >> 16) & 1u);           // RNE
  return (unsigned short)(u >> 16);
}
DEVINL float bf2f(unsigned short h){ return __uint_as_float(((unsigned)h) << 16); }

DEVINL void gload_lds16(const unsigned short* g, unsigned short* lds){
  __builtin_amdgcn_global_load_lds(
      (__attribute__((address_space(1))) unsigned int*)(g),
      (__attribute__((address_space(3))) unsigned int*)(lds), 16, 0, 0);
}

// ---- W [K][Nn] f32 -> Wt [Nn][K] bf16
__global__ __launch_bounds__(256) void transpose_cvt_kernel(const float* __restrict__ W,
                                                            unsigned short* __restrict__ Wt,
                                                            int K, int Nn){
  __shared__ float tile[32][33];
  int k0 = blockIdx.x*32, n0 = blockIdx.y*32;
  int tx = threadIdx.x & 31, ty = threadIdx.x >> 5;
  #pragma unroll
  for (int r = ty; r < 32; r += 8) tile[r][tx] = W[(size_t)(k0+r)*Nn + n0 + tx];
  __syncthreads();
  #pragma unroll
  for (int r = ty; r < 32; r += 8) Wt[(size_t)(n0+r)*K + k0 + tx] = f2bf(tile[tx][r]);
}

// ---- CSR build
__global__ __launch_bounds__(256) void hist_kernel(const int* __restrict__ dst,
                                                   int* __restrict__ deg, int E_){
  int i = blockIdx.x*256 + threadIdx.x;
  if (i < E_) atomicAdd(&deg[dst[i]], 1);
}

__global__ __launch_bounds__(256) void scan_kernel(const int* __restrict__ deg,
                                                   int* __restrict__ off, int n){
  const int CH = (n + 255) / 256;
  int t = threadIdx.x;
  int lo = t*CH, hi = min(lo + CH, n);
  int s = 0;
  for (int i = lo; i < hi; i++) s += deg[i];
  __shared__ int ws[256];
  ws[t] = s;
  __syncthreads();
  for (int d = 1; d < 256; d <<= 1){
    int v = (t >= d) ? ws[t-d] : 0;
    __syncthreads();
    ws[t] += v;
    __syncthreads();
  }
  int run = ws[t] - s;
  for (int i = lo; i < hi; i++){ off[i] = run; run += deg[i]; }
  if (t == 255) off[n] = ws[255];
}

__global__ __launch_bounds__(256) void scatter_kernel(const int* __restrict__ src,
                                                      const int* __restrict__ dst,
                                                      const int* __restrict__ off,
                                                      int* __restrict__ cursor,
                                                      int* __restrict__ csrc, int E_){
  int i = blockIdx.x*256 + threadIdx.x;
  if (i >= E_) return;
  int d = dst[i];
  int pI = atomicAdd(&cursor[d], 1);
  csrc[off[d] + pI] = src[i];
}

// ---- Wa1[c][i] = sum_j W1[c][h*256+j] * a1{s,d}[h][j]
__global__ __launch_bounds__(256) void wa1_kernel(const float* __restrict__ W1,
                                                  const float* __restrict__ a1s,
                                                  const float* __restrict__ a1d,
                                                  float* __restrict__ Wa1){
  int t = blockIdx.x*256 + threadIdx.x;
  if (t >= 64*16) return;
  int c = t >> 4, i = t & 15;
  int h = i & 7;
  const float* a = (i < 8) ? a1s : a1d;
  float s = 0.f;
  #pragma unroll 8
  for (int j = 0; j < 256; j++) s = fmaf(W1[(size_t)c*F12 + h*256 + j], a[h*256 + j], s);
  Wa1[c*16 + i] = s;
}

// ---- layer-1 logits straight from x
__global__ __launch_bounds__(256) void logits1_kernel(const float* __restrict__ x,
                                                      const float* __restrict__ Wa1,
                                                      float* __restrict__ als,
                                                      float* __restrict__ ald){
  __shared__ float wa[64*16];
  for (int i = threadIdx.x; i < 64*16; i += 256) wa[i] = Wa1[i];
  __syncthreads();
  int gid = blockIdx.x*256 + threadIdx.x;
  int v = gid >> 4, i = gid & 15;
  if (v >= NN) return;
  float s = 0.f;
  #pragma unroll
  for (int c = 0; c < 64; c++) s = fmaf(x[(size_t)v*64 + c], wa[c*16 + i], s);
  if (i < 8) als[v*8 + i] = s;
  else       ald[v*8 + (i - 8)] = s;
}

// ---- combine logits partials (4 slots)
__global__ __launch_bounds__(256) void combine_kernel(const float* __restrict__ pls,
                                                      const float* __restrict__ pld,
                                                      float* __restrict__ als,
                                                      float* __restrict__ ald,
                                                      int count){
  int i = blockIdx.x*256 + threadIdx.x;
  if (i >= count) return;
  als[i] = (pls[i] + pls[PSTR + i]) + (pls[2*PSTR + i] + pls[3*PSTR + i]);
  ald[i] = (pld[i] + pld[PSTR + i]) + (pld[2*PSTR + i] + pld[3*PSTR + i]);
}

// ---- layer-1 aggregation (R13): lane=(edge_slot,head) softmax, LDS alpha stage
__global__ __launch_bounds__(256) void agg1_kernel(const float* __restrict__ x,
                                                   const int* __restrict__ off,
                                                   const int* __restrict__ csrc,
                                                   const float* __restrict__ als,
                                                   const float* __restrict__ ald,
                                                   unsigned short* __restrict__ Xa){
  const int wv = threadIdx.x >> 6, lane = threadIdx.x & 63;
  const int v = blockIdx.x*4 + wv;
  if (v >= NN) return;
  const int e0 = off[v], deg = off[v+1] - e0;
  const int h  = lane & 7;
  const int es = lane >> 3;

  __shared__ float al_sh[4][64];
  __shared__ int   u_sh[4][8];

  const float aldv = ald[v*8 + h];

  float m = -1e30f, s = 0.f;
  for (int i = es; i < deg; i += 8){
    int u = csrc[e0 + i];
    float xe = als[u*8 + h] + aldv;
    xe = xe > 0.f ? xe : 0.2f*xe;
    float nm = fmaxf(m, xe);
    s = s*__expf(m - nm) + __expf(xe - nm);
    m = nm;
  }
  #pragma unroll
  for (int d = 8; d < 64; d <<= 1){
    float mo = __shfl_xor(m, d);
    float so = __shfl_xor(s, d);
    float nm = fmaxf(m, mo);
    s = s*__expf(m - nm) + so*__expf(mo - nm);
    m = nm;
  }
  const float sinv = 1.f / (s + 1e-16f);

  float acc[8];
  #pragma unroll
  for (int hh = 0; hh < 8; hh++) acc[hh] = 0.f;

  const int nfull = deg & ~7;
  for (int base = 0; base < nfull; base += 8){
    int u = csrc[e0 + base + es];
    if (h == 0) u_sh[wv][es] = u;
    float xe = als[u*8 + h] + aldv;
    xe = xe > 0.f ? xe : 0.2f*xe;
    al_sh[wv][es*8 + h] = __expf(xe - m) * sinv;
    #pragma unroll
    for (int j = 0; j < 8; j++){
      float xv = x[(size_t)u_sh[wv][j]*64 + lane];
      #pragma unroll
      for (int hh = 0; hh < 8; hh++)
        acc[hh] = fmaf(al_sh[wv][j*8 + hh], xv, acc[hh]);
    }
  }
  if (nfull < deg){
    const int nch = deg - nfull;
    if (es < nch){
      int u = csrc[e0 + nfull + es];
      if (h == 0) u_sh[wv][es] = u;
      float xe = als[u*8 + h] + aldv;
      xe = xe > 0.f ? xe : 0.2f*xe;
      al_sh[wv][es*8 + h] = __expf(xe - m) * sinv;
    }
    for (int j = 0; j < nch; j++){
      float xv = x[(size_t)u_sh[wv][j]*64 + lane];
      #pragma unroll
      for (int hh = 0; hh < 8; hh++)
        acc[hh] = fmaf(al_sh[wv][j*8 + hh], xv, acc[hh]);
    }
  }

  #pragma unroll
  for (int hh = 0; hh < 8; hh++)
    Xa[(size_t)v*512 + hh*64 + lane] = f2bf(acc[hh]);
}

// ---- layer-1 GEMM per head with fused bias+ELU
__global__ __launch_bounds__(256) void gemm_l1_kernel(
    const unsigned short* __restrict__ Xa,    // [MPAD][8][64]
    const unsigned short* __restrict__ Wt1,   // [2048][64]
    const float* __restrict__ b1,
    unsigned short* __restrict__ actA)        // [MPAD][2048]
{
  __shared__ __align__(16) unsigned short As[2][128*32];
  __shared__ __align__(16) unsigned short Bs[2][256*32];
  const int wave = threadIdx.x >> 6, lane = threadIdx.x & 63;
  const int wm = wave >> 1, wn = wave & 1;
  const size_t m0 = (size_t)blockIdx.x * 128;
  const int h = blockIdx.y;
  const int lr = lane >> 2, l3 = lane & 3;

  #pragma unroll
  for (int sB = 0; sB < 2; sB++){
    #pragma unroll
    for (int j = 0; j < 2; j++){
      int rb = (wave*2 + j)*16;
      int row = rb + lr;
      int kc = l3 ^ ((row >> 1) & 3);
      gload_lds16(Xa + (m0 + row)*512 + h*64 + sB*32 + kc*8, &As[sB][rb*32]);
    }
    #pragma unroll
    for (int j = 0; j < 4; j++){
      int rb = (wave*4 + j)*16;
      int row = rb + lr;
      int kc = l3 ^ ((row >> 1) & 3);
      gload_lds16(Wt1 + (size_t)(h*256 + row)*64 + sB*32 + kc*8, &Bs[sB][rb*32]);
    }
  }
  asm volatile("s_waitcnt vmcnt(0)" ::: "memory");
  __syncthreads();

  f32x4 acc[4][8];
  #pragma unroll
  for (int i = 0; i < 4; i++)
    #pragma unroll
    for (int j = 0; j < 8; j++) acc[i][j] = (f32x4){0.f,0.f,0.f,0.f};

  const int rl = lane & 15, q = lane >> 4;
  #pragma unroll
  for (int sB = 0; sB < 2; sB++){
    bf16x8 af[4], bfr[8];
    #pragma unroll
    for (int mm = 0; mm < 4; mm++){
      int row = wm*64 + mm*16 + rl;
      int ch = q ^ ((row >> 1) & 3);
      af[mm] = *(const bf16x8*)&As[sB][row*32 + ch*8];
    }
    #pragma unroll
    for (int n = 0; n < 8; n++){
      int row = wn*128 + n*16 + rl;
      int ch = q ^ ((row >> 1) & 3);
      bfr[n] = *(const bf16x8*)&Bs[sB][row*32 + ch*8];
    }
    #pragma unroll
    for (int mm = 0; mm < 4; mm++)
      #pragma unroll
      for (int n = 0; n < 8; n++)
        acc[mm][n] = __builtin_amdgcn_mfma_f32_16x16x32_bf16(af[mm], bfr[n], acc[mm][n], 0, 0, 0);
  }

  #pragma unroll
  for (int mm = 0; mm < 4; mm++)
    #pragma unroll
    for (int n = 0; n < 8; n++)
      #pragma unroll
      for (int r = 0; r < 4; r++){
        size_t row = m0 + wm*64 + mm*16 + q*4 + r;
        int col = wn*128 + n*16 + rl;
        float o = acc[mm][n][r] + b1[h*256 + col];
        o = o > 0.f ? o : (__expf(o) - 1.f);
        actA[row*F12 + h*256 + col] = f2bf(o);
      }
}

// ---- layer-2 GEMM (R11 config) + fused logits partials (plain stores).
__global__ __launch_bounds__(512, 1) void gemm_l2_kernel(
    const unsigned short* __restrict__ A,
    const unsigned short* __restrict__ Bt,
    unsigned short* __restrict__ Chm,         // [8][MPAD][256]
    const float* __restrict__ as2,            // [8][256]
    const float* __restrict__ ad2,            // [8][256]
    float* __restrict__ pls,                  // [4][MPAD*8]
    float* __restrict__ pld,                  // [4][MPAD*8]
    int K)
{
  __shared__ __align__(16) unsigned short As[3][640*32];   // 3 x 40KB
  __shared__ __align__(16) unsigned short Bs[3][128*32];   // 3 x 8KB

  const int tid  = threadIdx.x;
  const int wave = tid >> 6, lane = tid & 63;
  const int wm = wave >> 1, wn = wave & 1;          // 4Mx2N, per-wave 160x64

  const int orig = blockIdx.x;
  const int wg   = (orig & 7) * 32 + (orig >> 3);
  const size_t m0 = (size_t)(wg >> 4) * 640;
  const size_t n0 = (size_t)(wg & 15) * 128;

  f32x4 acc[10][4];
  #pragma unroll
  for (int i = 0; i < 10; i++)
    #pragma unroll
    for (int j = 0; j < 4; j++) acc[i][j] = (f32x4){0.f,0.f,0.f,0.f};

  const int lr = lane >> 2;
  const int l3 = lane & 3;

  auto stageA = [&](int slot, int k0, int j){
    const int rb  = (wave*5 + j) * 16;
    const int row = rb + lr;
    const int kc  = l3 ^ ((row >> 1) & 3);
    gload_lds16(A + (m0 + row)*(size_t)K + k0 + kc*8, &As[slot][rb*32]);
  };
  auto stageB = [&](int slot, int k0){
    const int rb  = wave * 16;
    const int row = rb + lr;
    const int kc  = l3 ^ ((row >> 1) & 3);
    gload_lds16(Bt + (n0 + row)*(size_t)K + k0 + kc*8, &Bs[slot][rb*32]);
  };
  auto stageTile = [&](int T){
    const int slot = T % 3, k0 = T << 5;
    #pragma unroll
    for (int j = 0; j < 5; j++) stageA(slot, k0, j);
    stageB(slot, k0);
  };

  const int nt = K >> 5;            // 64
  stageTile(0);
  stageTile(1);

  const int rl = lane & 15;
  const int q  = lane >> 4;

  for (int T = 0; T < nt; ++T){
    if (T + 1 < nt) asm volatile("s_waitcnt vmcnt(6)" ::: "memory");
    else            asm volatile("s_waitcnt vmcnt(0)" ::: "memory");
    __builtin_amdgcn_s_barrier();

    const int slot = T % 3;
    const bool st  = (T + 2 < nt);
    const int s2   = (T + 2) % 3;
    const int k2   = (T + 2) << 5;

    bf16x8 bfr[4], af[5];
    #pragma unroll
    for (int n = 0; n < 4; n++){
      const int row = wn*64 + n*16 + rl;
      const int ch  = q ^ ((row >> 1) & 3);
      bfr[n] = *(const bf16x8*)&Bs[slot][row*32 + ch*8];
    }
    #pragma unroll
    for (int m = 0; m < 5; m++){
      const int row = wm*160 + m*16 + rl;
      const int ch  = q ^ ((row >> 1) & 3);
      af[m] = *(const bf16x8*)&As[slot][row*32 + ch*8];
    }
    if (st){ stageA(s2, k2, 0); stageA(s2, k2, 1); stageA(s2, k2, 2); }
    asm volatile("s_waitcnt lgkmcnt(0)" ::: "memory");
    __builtin_amdgcn_sched_barrier(0);
    __builtin_amdgcn_s_setprio(1);
    #pragma unroll
    for (int m = 0; m < 5; m++)
      #pragma unroll
      for (int n = 0; n < 4; n++)
        acc[m][n] = __builtin_amdgcn_mfma_f32_16x16x32_bf16(af[m], bfr[n], acc[m][n], 0, 0, 0);
    __builtin_amdgcn_s_setprio(0);
    __builtin_amdgcn_sched_barrier(0);
    #pragma unroll
    for (int m = 0; m < 5; m++){
      const int row = wm*160 + (m+5)*16 + rl;
      const int ch  = q ^ ((row >> 1) & 3);
      af[m] = *(const bf16x8*)&As[slot][row*32 + ch*8];
    }
    if (st){ stageA(s2, k2, 3); stageA(s2, k2, 4); stageB(s2, k2); }
    asm volatile("s_waitcnt lgkmcnt(0)" ::: "memory");
    __builtin_amdgcn_sched_barrier(0);
    __builtin_amdgcn_s_setprio(1);
    #pragma unroll
    for (int m = 0; m < 5; m++)
      #pragma unroll
      for (int n = 0; n < 4; n++)
        acc[m+5][n] = __builtin_amdgcn_mfma_f32_16x16x32_bf16(af[m], bfr[n], acc[m+5][n], 0, 0, 0);
    __builtin_amdgcn_s_setprio(0);
  }

  const int head = (int)(n0 >> 8);           // BN=128 within one 256-col head
  const int pslot = (((int)(n0 >> 7) & 1) << 1) | wn;   // 4 producers/(row,head)
  float asw[4], adw[4];
  #pragma unroll
  for (int n = 0; n < 4; n++){
    const int ch = (int)(n0 & 255) + wn*64 + n*16 + rl;
    asw[n] = as2[head*CCH + ch];
    adw[n] = ad2[head*CCH + ch];
  }
  #pragma unroll
  for (int m = 0; m < 10; m++)
    #pragma unroll
    for (int r = 0; r < 4; r++){
      const size_t row = m0 + wm*160 + m*16 + q*4 + r;
      float ps = 0.f, pd = 0.f;
      #pragma unroll
      for (int n = 0; n < 4; n++){
        const float cv = acc[m][n][r];
        ps = fmaf(cv, asw[n], ps);
        pd = fmaf(cv, adw[n], pd);
        const int ch = wn*64 + n*16 + rl + (int)(n0 & 255);
        Chm[((size_t)head*MPAD + row)*CCH + ch] = f2bf(cv);
      }
      #pragma unroll
      for (int d = 1; d < 16; d <<= 1){
        ps += __shfl_xor(ps, d);
        pd += __shfl_xor(pd, d);
      }
      if (rl == 0){
        pls[(size_t)pslot*PSTR + row*NH + head] = ps;
        pld[(size_t)pslot*PSTR + row*NH + head] = pd;
      }
    }
}

// ---- R18 layer-3 GEMM: BM=160, BN=128, BK=32 -> grid 64x2 = 128 blocks at
// 2/CU = all 256 CUs busy (old 128x128 left 96 idle). 256 thr / 4 waves
// (2Mx2N, per-wave 80x64). dbuf 36KB LDS; role-split staging (w0,w1: 5 A
// issues; w2,w3: 4 B issues), per-role vmcnt; stage into vacated slot.
// Fused logits partials, slot = nb*2 + wn. n-fast XCD chunks.
__global__ __launch_bounds__(256, 2) void gemm_l3_kernel(
    const unsigned short* __restrict__ A,
    const unsigned short* __restrict__ Bt,    // [256][2048]
    unsigned short* __restrict__ C,           // [MPAD][256]
    const float* __restrict__ as3,            // [256]
    const float* __restrict__ ad3,            // [256]
    float* __restrict__ pls,                  // [4][MPAD*8] (row-indexed)
    float* __restrict__ pld,
    int K)
{
  __shared__ __align__(16) unsigned short As[2][160*32];   // 2 x 10KB
  __shared__ __align__(16) unsigned short Bs[2][128*32];   // 2 x 8KB

  const int tid  = threadIdx.x;
  const int wave = tid >> 6, lane = tid & 63;
  const int wm = wave >> 1, wn = wave & 1;     // per-wave 80x64

  // n-fast XCD chunks: each XCD owns 16 consecutive wg = 8 M-panels x both N
  const int orig = blockIdx.x;                  // 0..127
  const int wg   = (orig & 7) * 16 + (orig >> 3);
  const int nb   = wg & 1;
  const size_t m0 = (size_t)(wg >> 1) * 160;
  const size_t n0 = (size_t)nb * 128;

  f32x4 acc[5][4];
  #pragma unroll
  for (int i = 0; i < 5; i++)
    #pragma unroll
    for (int j = 0; j < 4; j++) acc[i][j] = (f32x4){0.f,0.f,0.f,0.f};

  const int lr = lane >> 2;
  const int l3 = lane & 3;

  // role-split staging: waves 0,1 stage A rows (wave*80 .. +79), 5 issues;
  // waves 2,3 stage B rows ((wave-2)*64 .. +63), 4 issues.
  const int nIss = (wave < 2) ? 5 : 4;
  auto stageT = [&](int T){
    const int slot = T & 1, k0 = T << 5;
    if (wave < 2){
      #pragma unroll
      for (int j = 0; j < 5; j++){
        const int rb  = (wave*5 + j) * 16;
        const int row = rb + lr;
        const int kc  = l3 ^ ((row >> 1) & 3);
        gload_lds16(A + (m0 + row)*(size_t)K + k0 + kc*8, &As[slot][rb*32]);
      }
    } else {
      #pragma unroll
      for (int j = 0; j < 4; j++){
        const int rb  = ((wave - 2)*4 + j) * 16;
        const int row = rb + lr;
        const int kc  = l3 ^ ((row >> 1) & 3);
        gload_lds16(Bt + (n0 + row)*(size_t)K + k0 + kc*8, &Bs[slot][rb*32]);
      }
    }
  };

  const int nt = K >> 5;            // 64
  stageT(0);
  stageT(1);

  const int rl = lane & 15;
  const int q  = lane >> 4;

  for (int T = 0; T < nt; ++T){
    // T's data landed when T+1's own-role issues remain in flight
    if (T + 1 < nt){
      if (wave < 2) asm volatile("s_waitcnt vmcnt(5)" ::: "memory");
      else          asm volatile("s_waitcnt vmcnt(4)" ::: "memory");
    } else {
      asm volatile("s_waitcnt vmcnt(0)" ::: "memory");
    }
    __builtin_amdgcn_s_barrier();            // (1) staged data visible

    const int cur = T & 1;
    bf16x8 af[5], bfr[4];
    #pragma unroll
    for (int m = 0; m < 5; m++){
      const int row = wm*80 + m*16 + rl;
      const int ch  = q ^ ((row >> 1) & 3);
      af[m] = *(const bf16x8*)&As[cur][row*32 + ch*8];
    }
    #pragma unroll
    for (int n = 0; n < 4; n++){
      const int row = wn*64 + n*16 + rl;
      const int ch  = q ^ ((row >> 1) & 3);
      bfr[n] = *(const bf16x8*)&Bs[cur][row*32 + ch*8];
    }
    asm volatile("s_waitcnt lgkmcnt(0)" ::: "memory");
    __builtin_amdgcn_sched_barrier(0);
    __builtin_amdgcn_s_barrier();            // (2) all reads done -> slot free

    if (T + 2 < nt) stageT(T + 2);           // refill just-vacated slot

    __builtin_amdgcn_s_setprio(1);
    #pragma unroll
    for (int m = 0; m < 5; m++)
      #pragma unroll
      for (int n = 0; n < 4; n++)
        acc[m][n] = __builtin_amdgcn_mfma_f32_16x16x32_bf16(af[m], bfr[n], acc[m][n], 0, 0, 0);
    __builtin_amdgcn_s_setprio(0);
  }

  float asw[4], adw[4];
  #pragma unroll
  for (int n = 0; n < 4; n++){
    const int ch = (int)n0 + wn*64 + n*16 + rl;
    asw[n] = as3[ch];
    adw[n] = ad3[ch];
  }
  const int pslot = (nb << 1) | wn;
  #pragma unroll
  for (int m = 0; m < 5; m++)
    #pragma unroll
    for (int r = 0; r < 4; r++){
      const size_t row = m0 + wm*80 + m*16 + q*4 + r;
      float ps = 0.f, pd = 0.f;
      #pragma unroll
      for (int n = 0; n < 4; n++){
        const float cv = acc[m][n][r];
        ps = fmaf(cv, asw[n], ps);
        pd = fmaf(cv, adw[n], pd);
        const size_t col = n0 + wn*64 + n*16 + rl;
        C[row*(size_t)CCH + col] = f2bf(cv);
      }
      #pragma unroll
      for (int d = 1; d < 16; d <<= 1){
        ps += __shfl_xor(ps, d);
        pd += __shfl_xor(pd, d);
      }
      if (rl == 0){
        pls[(size_t)pslot*PSTR + row] = ps;
        pld[(size_t)pslot*PSTR + row] = pd;
      }
    }
}

// ---- wave-per-(v,head) segment softmax + aggregation + bias + ELU (R14 form)
template<int NHD>
__global__ __launch_bounds__(256) void aggw_kernel(
    const unsigned short* __restrict__ Hm,
    const int* __restrict__ off, const int* __restrict__ csrc,
    const float* __restrict__ als, const float* __restrict__ ald,
    const float* __restrict__ bias,
    unsigned short* __restrict__ actout,
    float* __restrict__ fout)
{
  const int wv = threadIdx.x >> 6, lane = threadIdx.x & 63;
  const int hl = lane >> 5;
  const int li = lane & 31;
  int v, h;
  if constexpr (NHD == 8){
    h = blockIdx.x & 7;
    v = (blockIdx.x >> 3) * 4 + wv;
  } else {
    h = 0;
    v = blockIdx.x * 4 + wv;
  }
  if (v >= NN) return;
  const int e0 = off[v], deg = off[v+1] - e0;
  const float aldv = ald[v*NHD + h];

  __shared__ float al_sh[4][64];
  __shared__ int   u_sh[4][64];

  float mloc = -1e30f;
  for (int i = lane; i < deg; i += 64){
    int u = csrc[e0 + i];
    float xe = als[u*NHD + h] + aldv;
    xe = xe > 0.f ? xe : 0.2f*xe;
    mloc = fmaxf(mloc, xe);
  }
  #pragma unroll
  for (int d = 1; d < 64; d <<= 1) mloc = fmaxf(mloc, __shfl_xor(mloc, d));
  float sloc = 0.f;
  for (int i = lane; i < deg; i += 64){
    int u = csrc[e0 + i];
    float xe = als[u*NHD + h] + aldv;
    xe = xe > 0.f ? xe : 0.2f*xe;
    sloc += __expf(xe - mloc);
  }
  #pragma unroll
  for (int d = 1; d < 64; d <<= 1) sloc += __shfl_xor(sloc, d);
  const float sinv = 1.f / (sloc + 1e-16f);

  const unsigned short* hB = Hm + (size_t)h*MPAD*CCH + li*8;
  float acc[8];
  #pragma unroll
  for (int k = 0; k < 8; k++) acc[k] = 0.f;

  auto edge_fma = [&](const uint4& w, float a){
    acc[0] = fmaf(a, bf2f((unsigned short)(w.x & 0xffff)), acc[0]);
    acc[1] = fmaf(a, bf2f((unsigned short)(w.x >> 16)),    acc[1]);
    acc[2] = fmaf(a, bf2f((unsigned short)(w.y & 0xffff)), acc[2]);
    acc[3] = fmaf(a, bf2f((unsigned short)(w.y >> 16)),    acc[3]);
    acc[4] = fmaf(a, bf2f((unsigned short)(w.z & 0xffff)), acc[4]);
    acc[5] = fmaf(a, bf2f((unsigned short)(w.z >> 16)),    acc[5]);
    acc[6] = fmaf(a, bf2f((unsigned short)(w.w & 0xffff)), acc[6]);
    acc[7] = fmaf(a, bf2f((unsigned short)(w.w >> 16)),    acc[7]);
  };

  for (int base = 0; base < deg; base += 64){
    const int nch = min(deg - base, 64);
    if (lane < nch){
      int u = csrc[e0 + base + lane];
      u_sh[wv][lane] = u;
      float xe = als[u*NHD + h] + aldv;
      xe = xe > 0.f ? xe : 0.2f*xe;
      al_sh[wv][lane] = __expf(xe - mloc) * sinv;
    }
    int j = 0;
    for (; j + 4 <= nch; j += 4){
      const int   ua = u_sh[wv][j + hl],     ub = u_sh[wv][j + 2 + hl];
      const float aa = al_sh[wv][j + hl],    ab = al_sh[wv][j + 2 + hl];
      uint4 wA = *(const uint4*)(hB + (size_t)ua*CCH);
      uint4 wB = *(const uint4*)(hB + (size_t)ub*CCH);
      edge_fma(wA, aa);
      edge_fma(wB, ab);
    }
    for (; j + 2 <= nch; j += 2){
      const int   ua = u_sh[wv][j + hl];
      const float aa = al_sh[wv][j + hl];
      uint4 wA = *(const uint4*)(hB + (size_t)ua*CCH);
      edge_fma(wA, aa);
    }
    if (j < nch && hl == 0){
      const int   ua = u_sh[wv][j];
      const float aa = al_sh[wv][j];
      uint4 wA = *(const uint4*)(hB + (size_t)ua*CCH);
      edge_fma(wA, aa);
    }
  }

  #pragma unroll
  for (int k = 0; k < 8; k++) acc[k] += __shfl_xor(acc[k], 32);

  if (hl == 0){
    const int c0 = h*CCH + li*8;
    float o[8];
    #pragma unroll
    for (int k = 0; k < 8; k++){
      o[k] = acc[k] + bias[c0 + k];
      o[k] = o[k] > 0.f ? o[k] : (__expf(o[k]) - 1.f);
    }
    if constexpr (NHD == 8){
      bf16x8 ov;
      #pragma unroll
      for (int k = 0; k < 8; k++) ov[k] = (short)f2bf(o[k]);
      *(bf16x8*)&actout[(size_t)v*F12 + c0] = ov;
    } else {
      float4 o0 = make_float4(o[0], o[1], o[2], o[3]);
      float4 o1 = make_float4(o[4], o[5], o[6], o[7]);
      *(float4*)(fout + (size_t)v*CCH + li*8)     = o0;
      *(float4*)(fout + (size_t)v*CCH + li*8 + 4) = o1;
    }
  }
}

extern "C" void kernel_launch(void* const* d_in, const int* in_sizes, int n_in,
                              void* d_out, int out_size, void* d_ws, size_t ws_size,
                              hipStream_t stream)
{
  const float* x   = (const float*)d_in[0];
  const int*   ei  = (const int*)d_in[1];
  const float* W1  = (const float*)d_in[2];
  const float* as1 = (const float*)d_in[3];
  const float* ad1 = (const float*)d_in[4];
  const float* b1  = (const float*)d_in[5];
  const float* W2  = (const float*)d_in[6];
  const float* as2 = (const float*)d_in[7];
  const float* ad2 = (const float*)d_in[8];
  const float* b2  = (const float*)d_in[9];
  const float* W3  = (const float*)d_in[10];
  const float* as3 = (const float*)d_in[11];
  const float* ad3 = (const float*)d_in[12];
  const float* b3  = (const float*)d_in[13];
  float* out = (float*)d_out;
  (void)in_sizes; (void)n_in; (void)out_size; (void)ws_size;

  char* p = (char*)d_ws;
  auto carve = [&](size_t bytes)->char* {
    char* r = p; p += (bytes + 255) & ~(size_t)255; return r;
  };
  unsigned short* actA = (unsigned short*)carve((size_t)MPAD*F12*2);
  unsigned short* hbuf = (unsigned short*)carve((size_t)MPAD*F12*2);  // head-major
  unsigned short* Wt1  = (unsigned short*)carve((size_t)F12*DIN*2);
  unsigned short* Wt2  = (unsigned short*)carve((size_t)F12*F12*2);
  unsigned short* Wt3  = (unsigned short*)carve((size_t)CCH*F12*2);
  float* als  = (float*)carve((size_t)NN*NH*4);
  float* ald  = (float*)carve((size_t)NN*NH*4);
  float* pls  = (float*)carve((size_t)4*PSTR*4);
  float* pld  = (float*)carve((size_t)4*PSTR*4);
  float* Wa1  = (float*)carve((size_t)64*16*4);
  int* deg    = (int*)carve((size_t)2*NN*4);      // deg + cursor contiguous
  int* cursor = deg + NN;
  int* off    = (int*)carve((size_t)(NN+1)*4);
  int* csrc   = (int*)carve((size_t)NE*4);
  unsigned short* Xa = hbuf;   // [MPAD][8][64] alias; dead before gemm_l2 writes hbuf

  const int* esrc = ei;
  const int* edst = ei + NE;

  // weight transposes
  transpose_cvt_kernel<<<dim3(DIN/32,  F12/32), 256, 0, stream>>>(W1, Wt1, DIN, F12);
  transpose_cvt_kernel<<<dim3(F12/32,  F12/32), 256, 0, stream>>>(W2, Wt2, F12, F12);
  transpose_cvt_kernel<<<dim3(F12/32,  CCH/32), 256, 0, stream>>>(W3, Wt3, F12, CCH);

  // CSR by dst (deg+cursor zeroed in one memset)
  hipMemsetAsync(deg, 0, (size_t)2*NN*4, stream);
  hist_kernel<<<(NE + 255)/256, 256, 0, stream>>>(edst, deg, NE);
  scan_kernel<<<1, 256, 0, stream>>>(deg, off, NN);
  scatter_kernel<<<(NE + 255)/256, 256, 0, stream>>>(esrc, edst, off, cursor, csrc, NE);

  // layer 1 (linearity restructure)
  wa1_kernel<<<4, 256, 0, stream>>>(W1, as1, ad1, Wa1);
  logits1_kernel<<<(NN*16 + 255)/256, 256, 0, stream>>>(x, Wa1, als, ald);
  hipMemsetAsync(Xa + (size_t)NN*512, 0, (size_t)(MPAD-NN)*512*2, stream);
  agg1_kernel<<<(NN + 3)/4, 256, 0, stream>>>(x, off, csrc, als, ald, Xa);
  gemm_l1_kernel<<<dim3(MPAD/128, NH), 256, 0, stream>>>(Xa, Wt1, b1, actA);

  // layer 2: GEMM with fused logits partials -> combine -> aggregate
  gemm_l2_kernel<<<256, 512, 0, stream>>>(actA, Wt2, hbuf, as2, ad2, pls, pld, F12);
  combine_kernel<<<(NN*NH + 255)/256, 256, 0, stream>>>(pls, pld, als, ald, NN*NH);
  aggw_kernel<8><<<((NN + 3)/4)*8, 256, 0, stream>>>(hbuf, off, csrc, als, ald, b2, actA, nullptr);

  // layer 3: zero-tail GEMM with fused logits partials -> combine -> aggregate
  gemm_l3_kernel<<<128, 256, 0, stream>>>(actA, Wt3, hbuf, as3, ad3, pls, pld, F12);
  combine_kernel<<<(NN + 255)/256, 256, 0, stream>>>(pls, pld, als, ald, NN);
  aggw_kernel<1><<<(NN + 3)/4, 256, 0, stream>>>(hbuf, off, csrc, als, ald, b3, nullptr, out);
}

// Round 19
// 308.412 us; speedup vs baseline: 1.1832x; 1.0211x over previous
//
#include <hip/hip_runtime.h>

// GAT 3-layer forward, MI355X gfx950.
// R19: launch consolidation -- 3 transposes merged into 1 kernel; Xa-pad
// memset folded into agg1 (grid covers MPAD). Per-kernel code frozen from R18.

typedef __attribute__((ext_vector_type(8))) short bf16x8;
typedef __attribute__((ext_vector_type(4))) float f32x4;

#define DEVINL __device__ __forceinline__

static constexpr int NN   = 10000;
static constexpr int NE   = 160000;
static constexpr int MPAD = 10240;   // 16*640, 64*160, 80*128
static constexpr int DIN  = 64;
static constexpr int CCH  = 256;
static constexpr int NH   = 8;
static constexpr int F12  = 2048;    // NH * CCH
static constexpr int PSTR = MPAD*NH; // partials slot stride

DEVINL unsigned short f2bf(float x){
  unsigned u = __float_as_uint(x);
  u += 0x7fffu + ((u >> 16) & 1u);           // RNE
  return (unsigned short)(u >> 16);
}
DEVINL float bf2f(unsigned short h){ return __uint_as_float(((unsigned)h) << 16); }

DEVINL void gload_lds16(const unsigned short* g, unsigned short* lds){
  __builtin_amdgcn_global_load_lds(
      (__attribute__((address_space(1))) unsigned int*)(g),
      (__attribute__((address_space(3))) unsigned int*)(lds), 16, 0, 0);
}

// ---- merged weight transposes: W [K][Nn] f32 -> Wt [Nn][K] bf16 for 3 weights
// grid: flat blocks; ranges [0, g1) -> W1 (64x2048), [g1, g1+g2) -> W2
// (2048x2048), [g1+g2, g1+g2+g3) -> W3 (2048x256).
__global__ __launch_bounds__(256) void transpose3_kernel(
    const float* __restrict__ W1, unsigned short* __restrict__ Wt1,
    const float* __restrict__ W2, unsigned short* __restrict__ Wt2,
    const float* __restrict__ W3, unsigned short* __restrict__ Wt3)
{
  constexpr int g1x = DIN/32,  g1y = F12/32;   // 2 x 64
  constexpr int g2x = F12/32,  g2y = F12/32;   // 64 x 64
  constexpr int g3x = F12/32,  g3y = CCH/32;   // 64 x 8
  constexpr int g1 = g1x*g1y, g2 = g2x*g2y;

  const float* W; unsigned short* Wt; int K, Nn, bx, by;
  int b = blockIdx.x;
  if (b < g1){ W = W1; Wt = Wt1; K = DIN; Nn = F12; bx = b % g1x; by = b / g1x; }
  else if (b < g1 + g2){ b -= g1; W = W2; Wt = Wt2; K = F12; Nn = F12; bx = b % g2x; by = b / g2x; }
  else { b -= g1 + g2; W = W3; Wt = Wt3; K = F12; Nn = CCH; bx = b % g3x; by = b / g3x; }

  __shared__ float tile[32][33];
  int k0 = bx*32, n0 = by*32;
  int tx = threadIdx.x & 31, ty = threadIdx.x >> 5;
  #pragma unroll
  for (int r = ty; r < 32; r += 8) tile[r][tx] = W[(size_t)(k0+r)*Nn + n0 + tx];
  __syncthreads();
  #pragma unroll
  for (int r = ty; r < 32; r += 8) Wt[(size_t)(n0+r)*K + k0 + tx] = f2bf(tile[tx][r]);
}

// ---- CSR build
__global__ __launch_bounds__(256) void hist_kernel(const int* __restrict__ dst,
                                                   int* __restrict__ deg, int E_){
  int i = blockIdx.x*256 + threadIdx.x;
  if (i < E_) atomicAdd(&deg[dst[i]], 1);
}

__global__ __launch_bounds__(256) void scan_kernel(const int* __restrict__ deg,
                                                   int* __restrict__ off, int n){
  const int CH = (n + 255) / 256;
  int t = threadIdx.x;
  int lo = t*CH, hi = min(lo + CH, n);
  int s = 0;
  for (int i = lo; i < hi; i++) s += deg[i];
  __shared__ int ws[256];
  ws[t] = s;
  __syncthreads();
  for (int d = 1; d < 256; d <<= 1){
    int v = (t >= d) ? ws[t-d] : 0;
    __syncthreads();
    ws[t] += v;
    __syncthreads();
  }
  int run = ws[t] - s;
  for (int i = lo; i < hi; i++){ off[i] = run; run += deg[i]; }
  if (t == 255) off[n] = ws[255];
}

__global__ __launch_bounds__(256) void scatter_kernel(const int* __restrict__ src,
                                                      const int* __restrict__ dst,
                                                      const int* __restrict__ off,
                                                      int* __restrict__ cursor,
                                                      int* __restrict__ csrc, int E_){
  int i = blockIdx.x*256 + threadIdx.x;
  if (i >= E_) return;
  int d = dst[i];
  int pI = atomicAdd(&cursor[d], 1);
  csrc[off[d] + pI] = src[i];
}

// ---- Wa1[c][i] = sum_j W1[c][h*256+j] * a1{s,d}[h][j]
__global__ __launch_bounds__(256) void wa1_kernel(const float* __restrict__ W1,
                                                  const float* __restrict__ a1s,
                                                  const float* __restrict__ a1d,
                                                  float* __restrict__ Wa1){
  int t = blockIdx.x*256 + threadIdx.x;
  if (t >= 64*16) return;
  int c = t >> 4, i = t & 15;
  int h = i & 7;
  const float* a = (i < 8) ? a1s : a1d;
  float s = 0.f;
  #pragma unroll 8
  for (int j = 0; j < 256; j++) s = fmaf(W1[(size_t)c*F12 + h*256 + j], a[h*256 + j], s);
  Wa1[c*16 + i] = s;
}

// ---- layer-1 logits straight from x
__global__ __launch_bounds__(256) void logits1_kernel(const float* __restrict__ x,
                                                      const float* __restrict__ Wa1,
                                                      float* __restrict__ als,
                                                      float* __restrict__ ald){
  __shared__ float wa[64*16];
  for (int i = threadIdx.x; i < 64*16; i += 256) wa[i] = Wa1[i];
  __syncthreads();
  int gid = blockIdx.x*256 + threadIdx.x;
  int v = gid >> 4, i = gid & 15;
  if (v >= NN) return;
  float s = 0.f;
  #pragma unroll
  for (int c = 0; c < 64; c++) s = fmaf(x[(size_t)v*64 + c], wa[c*16 + i], s);
  if (i < 8) als[v*8 + i] = s;
  else       ald[v*8 + (i - 8)] = s;
}

// ---- combine logits partials (4 slots)
__global__ __launch_bounds__(256) void combine_kernel(const float* __restrict__ pls,
                                                      const float* __restrict__ pld,
                                                      float* __restrict__ als,
                                                      float* __restrict__ ald,
                                                      int count){
  int i = blockIdx.x*256 + threadIdx.x;
  if (i >= count) return;
  als[i] = (pls[i] + pls[PSTR + i]) + (pls[2*PSTR + i] + pls[3*PSTR + i]);
  ald[i] = (pld[i] + pld[PSTR + i]) + (pld[2*PSTR + i] + pld[3*PSTR + i]);
}

// ---- layer-1 aggregation (R13 form) + fused Xa padding (v in [NN, MPAD))
__global__ __launch_bounds__(256) void agg1_kernel(const float* __restrict__ x,
                                                   const int* __restrict__ off,
                                                   const int* __restrict__ csrc,
                                                   const float* __restrict__ als,
                                                   const float* __restrict__ ald,
                                                   unsigned short* __restrict__ Xa){
  const int wv = threadIdx.x >> 6, lane = threadIdx.x & 63;
  const int v = blockIdx.x*4 + wv;
  if (v >= MPAD) return;
  if (v >= NN){                                // pad rows: write zeros
    #pragma unroll
    for (int hh = 0; hh < 8; hh++)
      Xa[(size_t)v*512 + hh*64 + lane] = 0;
    return;
  }
  const int e0 = off[v], deg = off[v+1] - e0;
  const int h  = lane & 7;
  const int es = lane >> 3;

  __shared__ float al_sh[4][64];
  __shared__ int   u_sh[4][8];

  const float aldv = ald[v*8 + h];

  float m = -1e30f, s = 0.f;
  for (int i = es; i < deg; i += 8){
    int u = csrc[e0 + i];
    float xe = als[u*8 + h] + aldv;
    xe = xe > 0.f ? xe : 0.2f*xe;
    float nm = fmaxf(m, xe);
    s = s*__expf(m - nm) + __expf(xe - nm);
    m = nm;
  }
  #pragma unroll
  for (int d = 8; d < 64; d <<= 1){
    float mo = __shfl_xor(m, d);
    float so = __shfl_xor(s, d);
    float nm = fmaxf(m, mo);
    s = s*__expf(m - nm) + so*__expf(mo - nm);
    m = nm;
  }
  const float sinv = 1.f / (s + 1e-16f);

  float acc[8];
  #pragma unroll
  for (int hh = 0; hh < 8; hh++) acc[hh] = 0.f;

  const int nfull = deg & ~7;
  for (int base = 0; base < nfull; base += 8){
    int u = csrc[e0 + base + es];
    if (h == 0) u_sh[wv][es] = u;
    float xe = als[u*8 + h] + aldv;
    xe = xe > 0.f ? xe : 0.2f*xe;
    al_sh[wv][es*8 + h] = __expf(xe - m) * sinv;
    #pragma unroll
    for (int j = 0; j < 8; j++){
      float xv = x[(size_t)u_sh[wv][j]*64 + lane];
      #pragma unroll
      for (int hh = 0; hh < 8; hh++)
        acc[hh] = fmaf(al_sh[wv][j*8 + hh], xv, acc[hh]);
    }
  }
  if (nfull < deg){
    const int nch = deg - nfull;
    if (es < nch){
      int u = csrc[e0 + nfull + es];
      if (h == 0) u_sh[wv][es] = u;
      float xe = als[u*8 + h] + aldv;
      xe = xe > 0.f ? xe : 0.2f*xe;
      al_sh[wv][es*8 + h] = __expf(xe - m) * sinv;
    }
    for (int j = 0; j < nch; j++){
      float xv = x[(size_t)u_sh[wv][j]*64 + lane];
      #pragma unroll
      for (int hh = 0; hh < 8; hh++)
        acc[hh] = fmaf(al_sh[wv][j*8 + hh], xv, acc[hh]);
    }
  }

  #pragma unroll
  for (int hh = 0; hh < 8; hh++)
    Xa[(size_t)v*512 + hh*64 + lane] = f2bf(acc[hh]);
}

// ---- layer-1 GEMM per head with fused bias+ELU
__global__ __launch_bounds__(256) void gemm_l1_kernel(
    const unsigned short* __restrict__ Xa,    // [MPAD][8][64]
    const unsigned short* __restrict__ Wt1,   // [2048][64]
    const float* __restrict__ b1,
    unsigned short* __restrict__ actA)        // [MPAD][2048]
{
  __shared__ __align__(16) unsigned short As[2][128*32];
  __shared__ __align__(16) unsigned short Bs[2][256*32];
  const int wave = threadIdx.x >> 6, lane = threadIdx.x & 63;
  const int wm = wave >> 1, wn = wave & 1;
  const size_t m0 = (size_t)blockIdx.x * 128;
  const int h = blockIdx.y;
  const int lr = lane >> 2, l3 = lane & 3;

  #pragma unroll
  for (int sB = 0; sB < 2; sB++){
    #pragma unroll
    for (int j = 0; j < 2; j++){
      int rb = (wave*2 + j)*16;
      int row = rb + lr;
      int kc = l3 ^ ((row >> 1) & 3);
      gload_lds16(Xa + (m0 + row)*512 + h*64 + sB*32 + kc*8, &As[sB][rb*32]);
    }
    #pragma unroll
    for (int j = 0; j < 4; j++){
      int rb = (wave*4 + j)*16;
      int row = rb + lr;
      int kc = l3 ^ ((row >> 1) & 3);
      gload_lds16(Wt1 + (size_t)(h*256 + row)*64 + sB*32 + kc*8, &Bs[sB][rb*32]);
    }
  }
  asm volatile("s_waitcnt vmcnt(0)" ::: "memory");
  __syncthreads();

  f32x4 acc[4][8];
  #pragma unroll
  for (int i = 0; i < 4; i++)
    #pragma unroll
    for (int j = 0; j < 8; j++) acc[i][j] = (f32x4){0.f,0.f,0.f,0.f};

  const int rl = lane & 15, q = lane >> 4;
  #pragma unroll
  for (int sB = 0; sB < 2; sB++){
    bf16x8 af[4], bfr[8];
    #pragma unroll
    for (int mm = 0; mm < 4; mm++){
      int row = wm*64 + mm*16 + rl;
      int ch = q ^ ((row >> 1) & 3);
      af[mm] = *(const bf16x8*)&As[sB][row*32 + ch*8];
    }
    #pragma unroll
    for (int n = 0; n < 8; n++){
      int row = wn*128 + n*16 + rl;
      int ch = q ^ ((row >> 1) & 3);
      bfr[n] = *(const bf16x8*)&Bs[sB][row*32 + ch*8];
    }
    #pragma unroll
    for (int mm = 0; mm < 4; mm++)
      #pragma unroll
      for (int n = 0; n < 8; n++)
        acc[mm][n] = __builtin_amdgcn_mfma_f32_16x16x32_bf16(af[mm], bfr[n], acc[mm][n], 0, 0, 0);
  }

  #pragma unroll
  for (int mm = 0; mm < 4; mm++)
    #pragma unroll
    for (int n = 0; n < 8; n++)
      #pragma unroll
      for (int r = 0; r < 4; r++){
        size_t row = m0 + wm*64 + mm*16 + q*4 + r;
        int col = wn*128 + n*16 + rl;
        float o = acc[mm][n][r] + b1[h*256 + col];
        o = o > 0.f ? o : (__expf(o) - 1.f);
        actA[row*F12 + h*256 + col] = f2bf(o);
      }
}

// ---- layer-2 GEMM (R11 config) + fused logits partials (plain stores).
__global__ __launch_bounds__(512, 1) void gemm_l2_kernel(
    const unsigned short* __restrict__ A,
    const unsigned short* __restrict__ Bt,
    unsigned short* __restrict__ Chm,         // [8][MPAD][256]
    const float* __restrict__ as2,            // [8][256]
    const float* __restrict__ ad2,            // [8][256]
    float* __restrict__ pls,                  // [4][MPAD*8]
    float* __restrict__ pld,                  // [4][MPAD*8]
    int K)
{
  __shared__ __align__(16) unsigned short As[3][640*32];   // 3 x 40KB
  __shared__ __align__(16) unsigned short Bs[3][128*32];   // 3 x 8KB

  const int tid  = threadIdx.x;
  const int wave = tid >> 6, lane = tid & 63;
  const int wm = wave >> 1, wn = wave & 1;          // 4Mx2N, per-wave 160x64

  const int orig = blockIdx.x;
  const int wg   = (orig & 7) * 32 + (orig >> 3);
  const size_t m0 = (size_t)(wg >> 4) * 640;
  const size_t n0 = (size_t)(wg & 15) * 128;

  f32x4 acc[10][4];
  #pragma unroll
  for (int i = 0; i < 10; i++)
    #pragma unroll
    for (int j = 0; j < 4; j++) acc[i][j] = (f32x4){0.f,0.f,0.f,0.f};

  const int lr = lane >> 2;
  const int l3 = lane & 3;

  auto stageA = [&](int slot, int k0, int j){
    const int rb  = (wave*5 + j) * 16;
    const int row = rb + lr;
    const int kc  = l3 ^ ((row >> 1) & 3);
    gload_lds16(A + (m0 + row)*(size_t)K + k0 + kc*8, &As[slot][rb*32]);
  };
  auto stageB = [&](int slot, int k0){
    const int rb  = wave * 16;
    const int row = rb + lr;
    const int kc  = l3 ^ ((row >> 1) & 3);
    gload_lds16(Bt + (n0 + row)*(size_t)K + k0 + kc*8, &Bs[slot][rb*32]);
  };
  auto stageTile = [&](int T){
    const int slot = T % 3, k0 = T << 5;
    #pragma unroll
    for (int j = 0; j < 5; j++) stageA(slot, k0, j);
    stageB(slot, k0);
  };

  const int nt = K >> 5;            // 64
  stageTile(0);
  stageTile(1);

  const int rl = lane & 15;
  const int q  = lane >> 4;

  for (int T = 0; T < nt; ++T){
    if (T + 1 < nt) asm volatile("s_waitcnt vmcnt(6)" ::: "memory");
    else            asm volatile("s_waitcnt vmcnt(0)" ::: "memory");
    __builtin_amdgcn_s_barrier();

    const int slot = T % 3;
    const bool st  = (T + 2 < nt);
    const int s2   = (T + 2) % 3;
    const int k2   = (T + 2) << 5;

    bf16x8 bfr[4], af[5];
    #pragma unroll
    for (int n = 0; n < 4; n++){
      const int row = wn*64 + n*16 + rl;
      const int ch  = q ^ ((row >> 1) & 3);
      bfr[n] = *(const bf16x8*)&Bs[slot][row*32 + ch*8];
    }
    #pragma unroll
    for (int m = 0; m < 5; m++){
      const int row = wm*160 + m*16 + rl;
      const int ch  = q ^ ((row >> 1) & 3);
      af[m] = *(const bf16x8*)&As[slot][row*32 + ch*8];
    }
    if (st){ stageA(s2, k2, 0); stageA(s2, k2, 1); stageA(s2, k2, 2); }
    asm volatile("s_waitcnt lgkmcnt(0)" ::: "memory");
    __builtin_amdgcn_sched_barrier(0);
    __builtin_amdgcn_s_setprio(1);
    #pragma unroll
    for (int m = 0; m < 5; m++)
      #pragma unroll
      for (int n = 0; n < 4; n++)
        acc[m][n] = __builtin_amdgcn_mfma_f32_16x16x32_bf16(af[m], bfr[n], acc[m][n], 0, 0, 0);
    __builtin_amdgcn_s_setprio(0);
    __builtin_amdgcn_sched_barrier(0);
    #pragma unroll
    for (int m = 0; m < 5; m++){
      const int row = wm*160 + (m+5)*16 + rl;
      const int ch  = q ^ ((row >> 1) & 3);
      af[m] = *(const bf16x8*)&As[slot][row*32 + ch*8];
    }
    if (st){ stageA(s2, k2, 3); stageA(s2, k2, 4); stageB(s2, k2); }
    asm volatile("s_waitcnt lgkmcnt(0)" ::: "memory");
    __builtin_amdgcn_sched_barrier(0);
    __builtin_amdgcn_s_setprio(1);
    #pragma unroll
    for (int m = 0; m < 5; m++)
      #pragma unroll
      for (int n = 0; n < 4; n++)
        acc[m+5][n] = __builtin_amdgcn_mfma_f32_16x16x32_bf16(af[m], bfr[n], acc[m+5][n], 0, 0, 0);
    __builtin_amdgcn_s_setprio(0);
  }

  const int head = (int)(n0 >> 8);           // BN=128 within one 256-col head
  const int pslot = (((int)(n0 >> 7) & 1) << 1) | wn;   // 4 producers/(row,head)
  float asw[4], adw[4];
  #pragma unroll
  for (int n = 0; n < 4; n++){
    const int ch = (int)(n0 & 255) + wn*64 + n*16 + rl;
    asw[n] = as2[head*CCH + ch];
    adw[n] = ad2[head*CCH + ch];
  }
  #pragma unroll
  for (int m = 0; m < 10; m++)
    #pragma unroll
    for (int r = 0; r < 4; r++){
      const size_t row = m0 + wm*160 + m*16 + q*4 + r;
      float ps = 0.f, pd = 0.f;
      #pragma unroll
      for (int n = 0; n < 4; n++){
        const float cv = acc[m][n][r];
        ps = fmaf(cv, asw[n], ps);
        pd = fmaf(cv, adw[n], pd);
        const int ch = wn*64 + n*16 + rl + (int)(n0 & 255);
        Chm[((size_t)head*MPAD + row)*CCH + ch] = f2bf(cv);
      }
      #pragma unroll
      for (int d = 1; d < 16; d <<= 1){
        ps += __shfl_xor(ps, d);
        pd += __shfl_xor(pd, d);
      }
      if (rl == 0){
        pls[(size_t)pslot*PSTR + row*NH + head] = ps;
        pld[(size_t)pslot*PSTR + row*NH + head] = pd;
      }
    }
}

// ---- R18 layer-3 GEMM: BM=160, BN=128 -> 128 blocks x 2/CU, fused partials.
__global__ __launch_bounds__(256, 2) void gemm_l3_kernel(
    const unsigned short* __restrict__ A,
    const unsigned short* __restrict__ Bt,    // [256][2048]
    unsigned short* __restrict__ C,           // [MPAD][256]
    const float* __restrict__ as3,            // [256]
    const float* __restrict__ ad3,            // [256]
    float* __restrict__ pls,                  // [4][MPAD*8] (row-indexed)
    float* __restrict__ pld,
    int K)
{
  __shared__ __align__(16) unsigned short As[2][160*32];   // 2 x 10KB
  __shared__ __align__(16) unsigned short Bs[2][128*32];   // 2 x 8KB

  const int tid  = threadIdx.x;
  const int wave = tid >> 6, lane = tid & 63;
  const int wm = wave >> 1, wn = wave & 1;     // per-wave 80x64

  const int orig = blockIdx.x;                  // 0..127
  const int wg   = (orig & 7) * 16 + (orig >> 3);
  const int nb   = wg & 1;
  const size_t m0 = (size_t)(wg >> 1) * 160;
  const size_t n0 = (size_t)nb * 128;

  f32x4 acc[5][4];
  #pragma unroll
  for (int i = 0; i < 5; i++)
    #pragma unroll
    for (int j = 0; j < 4; j++) acc[i][j] = (f32x4){0.f,0.f,0.f,0.f};

  const int lr = lane >> 2;
  const int l3 = lane & 3;

  auto stageT = [&](int T){
    const int slot = T & 1, k0 = T << 5;
    if (wave < 2){
      #pragma unroll
      for (int j = 0; j < 5; j++){
        const int rb  = (wave*5 + j) * 16;
        const int row = rb + lr;
        const int kc  = l3 ^ ((row >> 1) & 3);
        gload_lds16(A + (m0 + row)*(size_t)K + k0 + kc*8, &As[slot][rb*32]);
      }
    } else {
      #pragma unroll
      for (int j = 0; j < 4; j++){
        const int rb  = ((wave - 2)*4 + j) * 16;
        const int row = rb + lr;
        const int kc  = l3 ^ ((row >> 1) & 3);
        gload_lds16(Bt + (n0 + row)*(size_t)K + k0 + kc*8, &Bs[slot][rb*32]);
      }
    }
  };

  const int nt = K >> 5;            // 64
  stageT(0);
  stageT(1);

  const int rl = lane & 15;
  const int q  = lane >> 4;

  for (int T = 0; T < nt; ++T){
    if (T + 1 < nt){
      if (wave < 2) asm volatile("s_waitcnt vmcnt(5)" ::: "memory");
      else          asm volatile("s_waitcnt vmcnt(4)" ::: "memory");
    } else {
      asm volatile("s_waitcnt vmcnt(0)" ::: "memory");
    }
    __builtin_amdgcn_s_barrier();            // (1) staged data visible

    const int cur = T & 1;
    bf16x8 af[5], bfr[4];
    #pragma unroll
    for (int m = 0; m < 5; m++){
      const int row = wm*80 + m*16 + rl;
      const int ch  = q ^ ((row >> 1) & 3);
      af[m] = *(const bf16x8*)&As[cur][row*32 + ch*8];
    }
    #pragma unroll
    for (int n = 0; n < 4; n++){
      const int row = wn*64 + n*16 + rl;
      const int ch  = q ^ ((row >> 1) & 3);
      bfr[n] = *(const bf16x8*)&Bs[cur][row*32 + ch*8];
    }
    asm volatile("s_waitcnt lgkmcnt(0)" ::: "memory");
    __builtin_amdgcn_sched_barrier(0);
    __builtin_amdgcn_s_barrier();            // (2) all reads done -> slot free

    if (T + 2 < nt) stageT(T + 2);           // refill just-vacated slot

    __builtin_amdgcn_s_setprio(1);
    #pragma unroll
    for (int m = 0; m < 5; m++)
      #pragma unroll
      for (int n = 0; n < 4; n++)
        acc[m][n] = __builtin_amdgcn_mfma_f32_16x16x32_bf16(af[m], bfr[n], acc[m][n], 0, 0, 0);
    __builtin_amdgcn_s_setprio(0);
  }

  float asw[4], adw[4];
  #pragma unroll
  for (int n = 0; n < 4; n++){
    const int ch = (int)n0 + wn*64 + n*16 + rl;
    asw[n] = as3[ch];
    adw[n] = ad3[ch];
  }
  const int pslot = (nb << 1) | wn;
  #pragma unroll
  for (int m = 0; m < 5; m++)
    #pragma unroll
    for (int r = 0; r < 4; r++){
      const size_t row = m0 + wm*80 + m*16 + q*4 + r;
      float ps = 0.f, pd = 0.f;
      #pragma unroll
      for (int n = 0; n < 4; n++){
        const float cv = acc[m][n][r];
        ps = fmaf(cv, asw[n], ps);
        pd = fmaf(cv, adw[n], pd);
        const size_t col = n0 + wn*64 + n*16 + rl;
        C[row*(size_t)CCH + col] = f2bf(cv);
      }
      #pragma unroll
      for (int d = 1; d < 16; d <<= 1){
        ps += __shfl_xor(ps, d);
        pd += __shfl_xor(pd, d);
      }
      if (rl == 0){
        pls[(size_t)pslot*PSTR + row] = ps;
        pld[(size_t)pslot*PSTR + row] = pd;
      }
    }
}

// ---- wave-per-(v,head) segment softmax + aggregation + bias + ELU (R14 form)
template<int NHD>
__global__ __launch_bounds__(256) void aggw_kernel(
    const unsigned short* __restrict__ Hm,
    const int* __restrict__ off, const int* __restrict__ csrc,
    const float* __restrict__ als, const float* __restrict__ ald,
    const float* __restrict__ bias,
    unsigned short* __restrict__ actout,
    float* __restrict__ fout)
{
  const int wv = threadIdx.x >> 6, lane = threadIdx.x & 63;
  const int hl = lane >> 5;
  const int li = lane & 31;
  int v, h;
  if constexpr (NHD == 8){
    h = blockIdx.x & 7;
    v = (blockIdx.x >> 3) * 4 + wv;
  } else {
    h = 0;
    v = blockIdx.x * 4 + wv;
  }
  if (v >= NN) return;
  const int e0 = off[v], deg = off[v+1] - e0;
  const float aldv = ald[v*NHD + h];

  __shared__ float al_sh[4][64];
  __shared__ int   u_sh[4][64];

  float mloc = -1e30f;
  for (int i = lane; i < deg; i += 64){
    int u = csrc[e0 + i];
    float xe = als[u*NHD + h] + aldv;
    xe = xe > 0.f ? xe : 0.2f*xe;
    mloc = fmaxf(mloc, xe);
  }
  #pragma unroll
  for (int d = 1; d < 64; d <<= 1) mloc = fmaxf(mloc, __shfl_xor(mloc, d));
  float sloc = 0.f;
  for (int i = lane; i < deg; i += 64){
    int u = csrc[e0 + i];
    float xe = als[u*NHD + h] + aldv;
    xe = xe > 0.f ? xe : 0.2f*xe;
    sloc += __expf(xe - mloc);
  }
  #pragma unroll
  for (int d = 1; d < 64; d <<= 1) sloc += __shfl_xor(sloc, d);
  const float sinv = 1.f / (sloc + 1e-16f);

  const unsigned short* hB = Hm + (size_t)h*MPAD*CCH + li*8;
  float acc[8];
  #pragma unroll
  for (int k = 0; k < 8; k++) acc[k] = 0.f;

  auto edge_fma = [&](const uint4& w, float a){
    acc[0] = fmaf(a, bf2f((unsigned short)(w.x & 0xffff)), acc[0]);
    acc[1] = fmaf(a, bf2f((unsigned short)(w.x >> 16)),    acc[1]);
    acc[2] = fmaf(a, bf2f((unsigned short)(w.y & 0xffff)), acc[2]);
    acc[3] = fmaf(a, bf2f((unsigned short)(w.y >> 16)),    acc[3]);
    acc[4] = fmaf(a, bf2f((unsigned short)(w.z & 0xffff)), acc[4]);
    acc[5] = fmaf(a, bf2f((unsigned short)(w.z >> 16)),    acc[5]);
    acc[6] = fmaf(a, bf2f((unsigned short)(w.w & 0xffff)), acc[6]);
    acc[7] = fmaf(a, bf2f((unsigned short)(w.w >> 16)),    acc[7]);
  };

  for (int base = 0; base < deg; base += 64){
    const int nch = min(deg - base, 64);
    if (lane < nch){
      int u = csrc[e0 + base + lane];
      u_sh[wv][lane] = u;
      float xe = als[u*NHD + h] + aldv;
      xe = xe > 0.f ? xe : 0.2f*xe;
      al_sh[wv][lane] = __expf(xe - mloc) * sinv;
    }
    int j = 0;
    for (; j + 4 <= nch; j += 4){
      const int   ua = u_sh[wv][j + hl],     ub = u_sh[wv][j + 2 + hl];
      const float aa = al_sh[wv][j + hl],    ab = al_sh[wv][j + 2 + hl];
      uint4 wA = *(const uint4*)(hB + (size_t)ua*CCH);
      uint4 wB = *(const uint4*)(hB + (size_t)ub*CCH);
      edge_fma(wA, aa);
      edge_fma(wB, ab);
    }
    for (; j + 2 <= nch; j += 2){
      const int   ua = u_sh[wv][j + hl];
      const float aa = al_sh[wv][j + hl];
      uint4 wA = *(const uint4*)(hB + (size_t)ua*CCH);
      edge_fma(wA, aa);
    }
    if (j < nch && hl == 0){
      const int   ua = u_sh[wv][j];
      const float aa = al_sh[wv][j];
      uint4 wA = *(const uint4*)(hB + (size_t)ua*CCH);
      edge_fma(wA, aa);
    }
  }

  #pragma unroll
  for (int k = 0; k < 8; k++) acc[k] += __shfl_xor(acc[k], 32);

  if (hl == 0){
    const int c0 = h*CCH + li*8;
    float o[8];
    #pragma unroll
    for (int k = 0; k < 8; k++){
      o[k] = acc[k] + bias[c0 + k];
      o[k] = o[k] > 0.f ? o[k] : (__expf(o[k]) - 1.f);
    }
    if constexpr (NHD == 8){
      bf16x8 ov;
      #pragma unroll
      for (int k = 0; k < 8; k++) ov[k] = (short)f2bf(o[k]);
      *(bf16x8*)&actout[(size_t)v*F12 + c0] = ov;
    } else {
      float4 o0 = make_float4(o[0], o[1], o[2], o[3]);
      float4 o1 = make_float4(o[4], o[5], o[6], o[7]);
      *(float4*)(fout + (size_t)v*CCH + li*8)     = o0;
      *(float4*)(fout + (size_t)v*CCH + li*8 + 4) = o1;
    }
  }
}

extern "C" void kernel_launch(void* const* d_in, const int* in_sizes, int n_in,
                              void* d_out, int out_size, void* d_ws, size_t ws_size,
                              hipStream_t stream)
{
  const float* x   = (const float*)d_in[0];
  const int*   ei  = (const int*)d_in[1];
  const float* W1  = (const float*)d_in[2];
  const float* as1 = (const float*)d_in[3];
  const float* ad1 = (const float*)d_in[4];
  const float* b1  = (const float*)d_in[5];
  const float* W2  = (const float*)d_in[6];
  const float* as2 = (const float*)d_in[7];
  const float* ad2 = (const float*)d_in[8];
  const float* b2  = (const float*)d_in[9];
  const float* W3  = (const float*)d_in[10];
  const float* as3 = (const float*)d_in[11];
  const float* ad3 = (const float*)d_in[12];
  const float* b3  = (const float*)d_in[13];
  float* out = (float*)d_out;
  (void)in_sizes; (void)n_in; (void)out_size; (void)ws_size;

  char* p = (char*)d_ws;
  auto carve = [&](size_t bytes)->char* {
    char* r = p; p += (bytes + 255) & ~(size_t)255; return r;
  };
  unsigned short* actA = (unsigned short*)carve((size_t)MPAD*F12*2);
  unsigned short* hbuf = (unsigned short*)carve((size_t)MPAD*F12*2);  // head-major
  unsigned short* Wt1  = (unsigned short*)carve((size_t)F12*DIN*2);
  unsigned short* Wt2  = (unsigned short*)carve((size_t)F12*F12*2);
  unsigned short* Wt3  = (unsigned short*)carve((size_t)CCH*F12*2);
  float* als  = (float*)carve((size_t)NN*NH*4);
  float* ald  = (float*)carve((size_t)NN*NH*4);
  float* pls  = (float*)carve((size_t)4*PSTR*4);
  float* pld  = (float*)carve((size_t)4*PSTR*4);
  float* Wa1  = (float*)carve((size_t)64*16*4);
  int* deg    = (int*)carve((size_t)2*NN*4);      // deg + cursor contiguous
  int* cursor = deg + NN;
  int* off    = (int*)carve((size_t)(NN+1)*4);
  int* csrc   = (int*)carve((size_t)NE*4);
  unsigned short* Xa = hbuf;   // [MPAD][8][64] alias; dead before gemm_l2 writes hbuf

  const int* esrc = ei;
  const int* edst = ei + NE;

  // merged weight transposes (1 launch): grids 128 + 4096 + 512
  transpose3_kernel<<<128 + 4096 + 512, 256, 0, stream>>>(W1, Wt1, W2, Wt2, W3, Wt3);

  // CSR by dst (deg+cursor zeroed in one memset)
  hipMemsetAsync(deg, 0, (size_t)2*NN*4, stream);
  hist_kernel<<<(NE + 255)/256, 256, 0, stream>>>(edst, deg, NE);
  scan_kernel<<<1, 256, 0, stream>>>(deg, off, NN);
  scatter_kernel<<<(NE + 255)/256, 256, 0, stream>>>(esrc, edst, off, cursor, csrc, NE);

  // layer 1 (linearity restructure); agg1 also zero-fills Xa pad rows
  wa1_kernel<<<4, 256, 0, stream>>>(W1, as1, ad1, Wa1);
  logits1_kernel<<<(NN*16 + 255)/256, 256, 0, stream>>>(x, Wa1, als, ald);
  agg1_kernel<<<MPAD/4, 256, 0, stream>>>(x, off, csrc, als, ald, Xa);
  gemm_l1_kernel<<<dim3(MPAD/128, NH), 256, 0, stream>>>(Xa, Wt1, b1, actA);

  // layer 2: GEMM with fused logits partials -> combine -> aggregate
  gemm_l2_kernel<<<256, 512, 0, stream>>>(actA, Wt2, hbuf, as2, ad2, pls, pld, F12);
  combine_kernel<<<(NN*NH + 255)/256, 256, 0, stream>>>(pls, pld, als, ald, NN*NH);
  aggw_kernel<8><<<((NN + 3)/4)*8, 256, 0, stream>>>(hbuf, off, csrc, als, ald, b2, actA, nullptr);

  // layer 3: zero-tail GEMM with fused logits partials -> combine -> aggregate
  gemm_l3_kernel<<<128, 256, 0, stream>>>(actA, Wt3, hbuf, as3, ad3, pls, pld, F12);
  combine_kernel<<<(NN + 255)/256, 256, 0, stream>>>(pls, pld, als, ald, NN);
  aggw_kernel<1><<<(NN + 3)/4, 256, 0, stream>>>(hbuf, off, csrc, als, ald, b3, nullptr, out);
}